// Round 16
// baseline (387.024 us; speedup 1.0000x reference)
//
#include <hip/hip_runtime.h>
#include <math.h>

// ---------------------------------------------------------------------------
// VQ-VAE forward, bf16-MFMA. Round 29: revert R28's dec1 x4 K-split (386.1,
// regression past the pre-committed falsifier) back to the R27 x2 config that
// measured 383.7us — grid (2,64,8), nchunks=4, k_dec1red sums 2 halves.
// Everything else identical to R27/R28.
// ---------------------------------------------------------------------------

typedef __bf16 bf16x8_t __attribute__((ext_vector_type(8)));
typedef _Float16 f16x8_t __attribute__((ext_vector_type(8)));
typedef float f32x4_t __attribute__((ext_vector_type(4)));
typedef _Float16 h2_t __attribute__((ext_vector_type(2)));

union FragU { uint4 u; bf16x8_t b; };
union Frag16 { uint4 u; f16x8_t h; };

__device__ inline f32x4_t mfma16(bf16x8_t a, bf16x8_t b, f32x4_t c) {
    return __builtin_amdgcn_mfma_f32_16x16x32_bf16(a, b, c, 0, 0, 0);
}
__device__ inline f32x4_t mfma16h(f16x8_t a, f16x8_t b, f32x4_t c) {
    return __builtin_amdgcn_mfma_f32_16x16x32_f16(a, b, c, 0, 0, 0);
}

__device__ inline void gl_lds16(const void* g, void* l) {
    __builtin_amdgcn_global_load_lds((const __attribute__((address_space(1))) void*)g,
                                     (__attribute__((address_space(3))) void*)l, 16, 0, 0);
}

__device__ inline unsigned bf16rne(float f) {
    unsigned u = __float_as_uint(f);
    u += 0x7FFFu + ((u >> 16) & 1u);
    return u >> 16;
}
__device__ inline unsigned pack2(float lo, float hi) {
    return bf16rne(lo) | (bf16rne(hi) << 16);
}
__device__ inline unsigned pack2h(float lo, float hi) {
    union { h2_t h; unsigned u; } r;
    r.h[0] = (_Float16)lo; r.h[1] = (_Float16)hi;
    return r.u;
}
__device__ inline unsigned short f16bits(float v) {
    union { _Float16 h; unsigned short s; } x; x.h = (_Float16)v; return x.s;
}
__device__ inline float f16lo(unsigned u) {
    union { unsigned u; h2_t h; } x; x.u = u; return (float)x.h[0];
}
__device__ inline float f16hi(unsigned u) {
    union { unsigned u; h2_t h; } x; x.u = u; return (float)x.h[1];
}
__device__ inline float bl(unsigned u) { return __uint_as_float(u << 16); }
__device__ inline float bh(unsigned u) { return __uint_as_float(u & 0xffff0000u); }

#if defined(__has_builtin)
#if __has_builtin(__builtin_amdgcn_fdot2)
#define HAS_FDOT2 1
#endif
#endif

__device__ inline float dot2h(unsigned x, unsigned w, float a) {
#ifdef HAS_FDOT2
    union { unsigned u; h2_t h; } ax, bw;
    ax.u = x; bw.u = w;
    return __builtin_amdgcn_fdot2(ax.h, bw.h, a, false);
#else
    union { unsigned u; _Float16 h[2]; } ax, bw;
    ax.u = x; bw.u = w;
    a = fmaf((float)ax.h[0], (float)bw.h[0], a);
    return fmaf((float)ax.h[1], (float)bw.h[1], a);
#endif
}
__device__ inline float dot8(uint4 x, uint4 w, float a) {
    a = dot2h(x.x, w.x, a); a = dot2h(x.y, w.y, a);
    a = dot2h(x.z, w.z, a); a = dot2h(x.w, w.w, a);
    return a;
}

// ---- generic implicit-GEMM conv (enc3, dec1) -------------------------------
// DBUF=1: double-buffered LDS; stage(ch+1) issued before compute(ch).
// OUTM==4: K-split partial mode — blockIdx.x selects the chunk-half, output
// is raw fp32 acc (no bias/relu) to [khalf][nb][4096pix][64ch].
template<int NR, int KW_, int SW, int CIC, int SPT, int NT, int OUTM, int DBUF>
__global__ __launch_bounds__(256) void conv_mfma(
    const unsigned short* __restrict__ in, const unsigned short* __restrict__ wp,
    const float* __restrict__ bias, void* __restrict__ outp,
    int Hp, int Wp, int PS, int nchunks, int Cout, int ncog,
    int Hpo, int Wpo, int relu)
{
    constexpr int W_ST = SW * (SPT - 1) + KW_;
    constexpr int SLOTS_PP = CIC / 8;
    constexpr int ROW_SLOTS = W_ST * SLOTS_PP;
    constexpr int SEGS = (ROW_SLOTS + 63) / 64;
    constexpr int KT = NR * KW_;
    constexpr int CSTEPS = CIC / 32;
    constexpr int BUFSZ = NR * W_ST * CIC;
    __shared__ __align__(16) unsigned short sh[(DBUF ? 2 : 1) * BUFSZ];

    int t = threadIdx.x, lane = t & 63, wv = t >> 6;
    int bx = blockIdx.x;
    int owt, khalf;
    if constexpr (OUTM == 4) { khalf = bx; owt = 0; }
    else { khalf = 0; owt = bx; }
    int ch0 = khalf * nchunks;
    int ohg = blockIdx.y;
    int bz = blockIdx.z; int nb = bz / ncog; int cog = bz % ncog;
    int ow0 = owt * SPT;
    int row0 = SW * ohg;
    int col0 = SW * ow0;
    int coh = wv & 1;
    int sph = wv >> 1;
    int m = lane & 15, g = lane >> 4;

    f32x4_t acc[2][NT];
#pragma unroll
    for (int a = 0; a < 2; ++a)
#pragma unroll
        for (int u2 = 0; u2 < NT; ++u2) acc[a][u2] = (f32x4_t){0.f, 0.f, 0.f, 0.f};

    auto stage = [&](int ch, unsigned short* buf) {
        for (int u_ = wv; u_ < NR * SEGS; u_ += 4) {
            int r = u_ / SEGS, seg = u_ - r * SEGS;
            int slot = seg * 64 + lane;
            int p = slot / SLOTS_PP;
            int uu = slot & (SLOTS_PP - 1);
            if (p < W_ST) {
                int su = (uu - (p & 7)) & (SLOTS_PP - 1);
                const unsigned short* gsrc = in +
                    (((size_t)nb * Hp + (row0 + r)) * Wp + (col0 + p)) * PS + (ch0 + ch) * CIC + su * 8;
                unsigned short* ldst = buf + ((size_t)(r * ROW_SLOTS + seg * 64 + lane)) * 8;
                gl_lds16(gsrc, ldst);
            }
        }
    };

    auto compute = [&](int ch, const unsigned short* buf) {
        int sbase = (ch0 + ch) * (KT * CSTEPS);
#pragma unroll
        for (int tap = 0; tap < KT; ++tap) {
            const int r_l = tap / KW_, kwp = tap % KW_;
#pragma unroll
            for (int cs = 0; cs < CSTEPS; ++cs) {
                int s = sbase + tap * CSTEPS + cs;
                const uint4* wr = (const uint4*)wp + (size_t)(s * 4 + g) * Cout + cog * 64 + coh * 32 + m;
                FragU a0, a1;
                a0.u = wr[0];
                a1.u = wr[16];
#pragma unroll
                for (int u2 = 0; u2 < NT; ++u2) {
                    int sp_l = sph * (SPT / 2) + u2 * 16 + m;
                    int p = SW * sp_l + kwp;
                    int off = (cs * 32 + g * 8 + ((p & 7) << 3)) & (CIC - 1);
                    FragU bb;
                    bb.u = *(const uint4*)(buf + (size_t)(r_l * W_ST + p) * CIC + off);
                    acc[0][u2] = mfma16(a0.b, bb.b, acc[0][u2]);
                    acc[1][u2] = mfma16(a1.b, bb.b, acc[1][u2]);
                }
            }
        }
    };

    stage(0, sh);
    __syncthreads();
    for (int ch = 0; ch < nchunks; ++ch) {
        if constexpr (DBUF != 0) {
            if (ch + 1 < nchunks) stage(ch + 1, sh + (size_t)((ch + 1) & 1) * BUFSZ);
        }
        compute(ch, DBUF ? (sh + (size_t)(ch & 1) * BUFSZ) : sh);
        if (ch + 1 < nchunks) {
            if constexpr (DBUF == 0) {
                __syncthreads();
                stage(ch + 1, sh);
            }
            __syncthreads();
        }
    }
    if constexpr (OUTM == 4) {
        float* ob = (float*)outp;
#pragma unroll
        for (int a = 0; a < 2; ++a) {
#pragma unroll
            for (int u2 = 0; u2 < NT; ++u2) {
                int ow = ow0 + sph * (SPT / 2) + u2 * 16 + m;
                float4 st = {acc[a][u2][0], acc[a][u2][1], acc[a][u2][2], acc[a][u2][3]};
                *(float4*)(ob + ((((size_t)khalf * 8 + nb) * 4096 + ohg * 64 + ow) * 64
                          + (coh * 32 + a * 16 + g * 4))) = st;
            }
        }
    } else {
#pragma unroll
        for (int a = 0; a < 2; ++a) {
            int co = cog * 64 + coh * 32 + a * 16 + g * 4;
            float4 bv = *(const float4*)(bias + co);
#pragma unroll
            for (int u2 = 0; u2 < NT; ++u2) {
                int ow = ow0 + sph * (SPT / 2) + u2 * 16 + m;
                float v0 = acc[a][u2][0] + bv.x;
                float v1 = acc[a][u2][1] + bv.y;
                float v2 = acc[a][u2][2] + bv.z;
                float v3 = acc[a][u2][3] + bv.w;
                if (relu) {
                    v0 = fmaxf(v0, 0.f); v1 = fmaxf(v1, 0.f);
                    v2 = fmaxf(v2, 0.f); v3 = fmaxf(v3, 0.f);
                }
                unsigned short* ob = (unsigned short*)outp;
                uint2 st;
                if constexpr (OUTM == 3) st = (uint2){pack2h(v0, v1), pack2h(v2, v3)};
                else                     st = (uint2){pack2(v0, v1), pack2(v2, v3)};
                *(uint2*)(ob + (((size_t)nb * Hpo + ohg + 1) * Wpo + (ow + 1)) * 64
                          + (coh * 32 + a * 16 + g * 4)) = st;
            }
        }
    }
}

// ---- dec1 K-split reduce: sum halves + bias + ReLU -> bf16 d1 halo ---------
__global__ __launch_bounds__(256) void k_dec1red(const float* __restrict__ pf,
    const float* __restrict__ bias, unsigned short* __restrict__ d1)
{
    int idx = blockIdx.x * 256 + threadIdx.x;     // 262144 total
    int c8 = idx & 7;
    int rest = idx >> 3;                          // n*4096 + pix
    int pix = rest & 4095, n = rest >> 12;
    const float* p0 = pf + (size_t)rest * 64 + c8 * 8;
    const float* p1 = p0 + (size_t)32768 * 64;
    float4 a0 = *(const float4*)p0, a1 = *(const float4*)(p0 + 4);
    float4 b0 = *(const float4*)p1, b1 = *(const float4*)(p1 + 4);
    float4 s0 = *(const float4*)(bias + c8 * 8);
    float4 s1 = *(const float4*)(bias + c8 * 8 + 4);
    float v0 = fmaxf(a0.x + b0.x + s0.x, 0.f);
    float v1 = fmaxf(a0.y + b0.y + s0.y, 0.f);
    float v2 = fmaxf(a0.z + b0.z + s0.z, 0.f);
    float v3 = fmaxf(a0.w + b0.w + s0.w, 0.f);
    float v4 = fmaxf(a1.x + b1.x + s1.x, 0.f);
    float v5 = fmaxf(a1.y + b1.y + s1.y, 0.f);
    float v6 = fmaxf(a1.z + b1.z + s1.z, 0.f);
    float v7 = fmaxf(a1.w + b1.w + s1.w, 0.f);
    uint4 st = {pack2(v0, v1), pack2(v2, v3), pack2(v4, v5), pack2(v6, v7)};
    int h = pix >> 6, w = pix & 63;
    *(uint4*)(d1 + ((size_t)(n * 66 + h + 1) * 66 + (w + 1)) * 64 + c8 * 8) = st;
}

// ---- enc2: 4x4 s2 conv 64->64, full-row blocks (64co x 128sp) --------------
__global__ __launch_bounds__(256) void k_enc2w(
    const unsigned short* __restrict__ in, const unsigned short* __restrict__ wp,
    const float* __restrict__ bias, unsigned short* __restrict__ out)
{
    __shared__ __align__(16) unsigned short sh[16512];   // 258 px x 64 ch
    int t = threadIdx.x, lane = t & 63, wv = t >> 6;
    int m = lane & 15, g = lane >> 4;
    int ohg = blockIdx.x, n = blockIdx.y;

    f32x4_t acc[4][2];
#pragma unroll
    for (int a = 0; a < 4; ++a)
#pragma unroll
        for (int u2 = 0; u2 < 2; ++u2) acc[a][u2] = (f32x4_t){0.f, 0.f, 0.f, 0.f};

    const uint4* wp4 = (const uint4*)wp;
#pragma unroll
    for (int kh = 0; kh < 4; ++kh) {
        if (kh) __syncthreads();
        const unsigned short* rowp = in + ((size_t)(n * 258 + 2 * ohg + kh) * 258) * 64;
        for (int q = t; q < 2064; q += 256) {
            int p = q >> 3, uu = q & 7;
            int su = (uu - ((p >> 1) & 7)) & 7;
            gl_lds16(rowp + (size_t)p * 64 + su * 8, sh + (size_t)q * 8);
        }
        __syncthreads();
#pragma unroll
        for (int kwp = 0; kwp < 4; ++kwp) {
#pragma unroll
            for (int cs = 0; cs < 2; ++cs) {
                int s = (kh * 4 + kwp) * 2 + cs;
                const uint4* wr = wp4 + (size_t)(s * 4 + g) * 64 + m;
                FragU A[4];
#pragma unroll
                for (int a = 0; a < 4; ++a) A[a].u = wr[a * 16];
#pragma unroll
                for (int u2 = 0; u2 < 2; ++u2) {
                    int sp_l = wv * 32 + u2 * 16 + m;
                    int p = 2 * sp_l + kwp;
                    int rot = (sp_l + (kwp >> 1)) & 7;
                    int off = (cs * 32 + g * 8 + rot * 8) & 63;
                    FragU B;
                    B.u = *(const uint4*)(sh + (size_t)p * 64 + off);
#pragma unroll
                    for (int a = 0; a < 4; ++a)
                        acc[a][u2] = mfma16(A[a].b, B.b, acc[a][u2]);
                }
            }
        }
    }
#pragma unroll
    for (int a = 0; a < 4; ++a) {
        float4 bv = *(const float4*)(bias + a * 16 + g * 4);
#pragma unroll
        for (int u2 = 0; u2 < 2; ++u2) {
            int ow = wv * 32 + u2 * 16 + m;
            float v0 = fmaxf(acc[a][u2][0] + bv.x, 0.f);
            float v1 = fmaxf(acc[a][u2][1] + bv.y, 0.f);
            float v2 = fmaxf(acc[a][u2][2] + bv.z, 0.f);
            float v3 = fmaxf(acc[a][u2][3] + bv.w, 0.f);
            uint2 st = {pack2(v0, v1), pack2(v2, v3)};
            *(uint2*)(out + ((size_t)(n * 130 + ohg + 1) * 130 + ow + 1) * 64
                      + a * 16 + g * 4) = st;
        }
    }
}

// ---- fused conv-transpose 4x4 s2: one output-row (ph) per block ------------
// ph-split for TLP — block stages 2 input rows (17KB LDS), waves split
// (pw, u2-half), acc[4][2]. Epilogue: contiguous-row store ([128][68] alias).
template<int OUTM>
__global__ __launch_bounds__(256) void k_convtf(
    const unsigned short* __restrict__ in, const unsigned short* __restrict__ wp,
    const float* __restrict__ bias, unsigned short* __restrict__ out,
    int Hpi, int Wpi, int Hpo, int Wpo)
{
    __shared__ __align__(16) unsigned short sh[8704];    // 2x528x8=8448 stage; alias [128][68]
    int t = threadIdx.x, lane = t & 63, wv = t >> 6;
    int m = lane & 15, g = lane >> 4;
    int pw = wv & 1, u2h = wv >> 1;
    int owt = blockIdx.x;
    int by = blockIdx.y; int ohg = by >> 1, ph = by & 1;
    int n = blockIdx.z;
    int col0 = owt * 64;

    const unsigned short* an = in + ((size_t)(n * Hpi + ohg + ph) * Wpi + col0) * 64;
    for (int q = t; q < 1056; q += 256) {
        int r = q / 528, rest = q - r * 528;
        int p = rest >> 3, uu = rest & 7;
        int su = (uu - (p & 7)) & 7;
        gl_lds16(an + ((size_t)r * Wpi + p) * 64 + su * 8, sh + (size_t)q * 8);
    }
    f32x4_t acc[4][2];
#pragma unroll
    for (int a = 0; a < 4; ++a)
#pragma unroll
        for (int u2i = 0; u2i < 2; ++u2i) acc[a][u2i] = (f32x4_t){0.f, 0.f, 0.f, 0.f};
    __syncthreads();

    const uint4* ws4 = (const uint4*)(wp + (size_t)(ph * 2 + pw) * 16384);
#pragma unroll
    for (int jh = 0; jh < 2; ++jh) {
#pragma unroll
        for (int jw = 0; jw < 2; ++jw) {
#pragma unroll
            for (int cs = 0; cs < 2; ++cs) {
                int s = (jh * 2 + jw) * 2 + cs;
                const uint4* wr = ws4 + (size_t)(s * 4 + g) * 64 + m;
                FragU A[4];
#pragma unroll
                for (int a = 0; a < 4; ++a) A[a].u = wr[a * 16];
#pragma unroll
                for (int u2i = 0; u2i < 2; ++u2i) {
                    int u2 = u2h * 2 + u2i;
                    int p = u2 * 16 + m + pw + jw;
                    int off = (cs * 32 + g * 8 + ((p & 7) << 3)) & 63;
                    FragU B;
                    B.u = *(const uint4*)(sh + (size_t)(jh * 528 + p * 8) * 8 + off);
#pragma unroll
                    for (int a = 0; a < 4; ++a)
                        acc[a][u2i] = mfma16(A[a].b, B.b, acc[a][u2i]);
                }
            }
        }
    }
    // epilogue: bias+relu+pack, LDS [128][68] alias, contiguous row store
    unsigned pk[4][2][2];
#pragma unroll
    for (int a = 0; a < 4; ++a) {
        float4 bv = *(const float4*)(bias + a * 16 + g * 4);
#pragma unroll
        for (int u2i = 0; u2i < 2; ++u2i) {
            float v0 = fmaxf(acc[a][u2i][0] + bv.x, 0.f);
            float v1 = fmaxf(acc[a][u2i][1] + bv.y, 0.f);
            float v2 = fmaxf(acc[a][u2i][2] + bv.z, 0.f);
            float v3 = fmaxf(acc[a][u2i][3] + bv.w, 0.f);
            if constexpr (OUTM == 3) { pk[a][u2i][0] = pack2h(v0, v1); pk[a][u2i][1] = pack2h(v2, v3); }
            else                     { pk[a][u2i][0] = pack2(v0, v1);  pk[a][u2i][1] = pack2(v2, v3); }
        }
    }
    __syncthreads();                             // stage reads done before alias
#pragma unroll
    for (int u2i = 0; u2i < 2; ++u2i) {
        int u2 = u2h * 2 + u2i;
        int lp = 2 * (u2 * 16 + m) + pw;         // local pixel 0..127
#pragma unroll
        for (int a = 0; a < 4; ++a)
            *(uint2*)(sh + (size_t)lp * 68 + a * 16 + g * 4) =
                (uint2){pk[a][u2i][0], pk[a][u2i][1]};
    }
    __syncthreads();
    unsigned short* gbase = out + ((size_t)(n * Hpo + 2 * ohg + ph + 1) * Wpo
                          + 2 * col0 + 1) * 64;
#pragma unroll
    for (int i = 0; i < 4; ++i) {
        int s = i * 256 + t;                     // 1024 uint4 slots = 128px x 64ch
        int p = s >> 3, c8 = s & 7;
        uint4 v = *(const uint4*)(sh + (size_t)p * 68 + c8 * 8);
        *(uint4*)(gbase + (size_t)s * 8) = v;
    }
}

// ---- enc4: 3x3 s1 conv 64->512, 128sp x 128co tiles ------------------------
__global__ __launch_bounds__(256) void k_enc4(
    const unsigned short* __restrict__ a3, const unsigned short* __restrict__ wp,
    const float* __restrict__ bias, unsigned short* __restrict__ zH,
    unsigned short* __restrict__ zL)
{
    __shared__ __align__(16) unsigned short sh[16896];
    int t = threadIdx.x, lane = t & 63, wv = t >> 6;
    int wc = wv & 1, wr = wv >> 1;
    int m = lane & 15, g = lane >> 4;
    int L = blockIdx.x;
    int xcd = L & 7, j = L >> 3;
    int cog = j & 3;
    int rt = (j >> 2) + xcd * 32;
    int row0 = rt * 128;
    int n = row0 >> 12;
    int oh0 = (row0 & 4095) >> 6;

    const unsigned short* an = a3 + ((size_t)(n * 66 + oh0) * 66) * 64;
    for (int seg = wv; seg < 33; seg += 4) {
        int slot = seg * 64 + lane;
        if (slot < 2112) {
            int r = slot / 528, rest = slot - r * 528;
            int p = rest >> 3, uu = rest & 7;
            int su = (uu - p) & 7;
            gl_lds16(an + ((size_t)(r * 66 + p)) * 64 + su * 8, sh + (size_t)slot * 8);
        }
    }
    f32x4_t acc[4][4];
#pragma unroll
    for (int a = 0; a < 4; ++a)
#pragma unroll
        for (int b = 0; b < 4; ++b) acc[a][b] = (f32x4_t){0.f, 0.f, 0.f, 0.f};
    __syncthreads();

#pragma unroll
    for (int tap = 0; tap < 9; ++tap) {
        const int kh = tap / 3, kwp = tap % 3;
#pragma unroll
        for (int cs = 0; cs < 2; ++cs) {
            int s = tap * 2 + cs;
            const uint4* wr4 = (const uint4*)wp + (size_t)(s * 4 + g) * 512 + cog * 128 + wc * 64 + m;
            FragU A[4];
#pragma unroll
            for (int ci = 0; ci < 4; ++ci) A[ci].u = wr4[ci * 16];
#pragma unroll
            for (int si = 0; si < 4; ++si) {
                int sp_l = wr * 64 + si * 16 + m;
                int r_l = (sp_l >> 6) + kh;
                int px = (sp_l & 63) + kwp;
                int off = (cs * 4 + g + px) & 7;
                FragU B;
                B.u = *(const uint4*)(sh + ((size_t)(r_l * 528 + px * 8 + off)) * 8);
#pragma unroll
                for (int ci = 0; ci < 4; ++ci)
                    acc[ci][si] = mfma16(A[ci].b, B.b, acc[ci][si]);
            }
        }
    }
    float4 bv[4];
#pragma unroll
    for (int ci = 0; ci < 4; ++ci)
        bv[ci] = *(const float4*)(bias + cog * 128 + wc * 64 + ci * 16 + g * 4);

    __syncthreads();
#pragma unroll
    for (int ci = 0; ci < 4; ++ci) {
#pragma unroll
        for (int si = 0; si < 4; ++si) {
            float v0 = acc[ci][si][0] + bv[ci].x;
            float v1 = acc[ci][si][1] + bv[ci].y;
            float v2 = acc[ci][si][2] + bv[ci].z;
            float v3 = acc[ci][si][3] + bv[ci].w;
            unsigned h0 = pack2h(v0, v1);
            unsigned h1 = pack2h(v2, v3);
            int row = wr * 64 + si * 16 + m;
            int col = wc * 64 + ci * 16 + g * 4;
            *(uint2*)(sh + (size_t)row * 132 + col) = (uint2){h0, h1};
        }
    }
    __syncthreads();
#pragma unroll
    for (int i = 0; i < 8; ++i) {
        int idx = i * 256 + t;
        int row = idx >> 4, c16 = idx & 15;
        uint4 v = *(const uint4*)(sh + (size_t)row * 132 + c16 * 8);
        int col = cog * 128 + c16 * 8;
        int sblk = col >> 5, off = col & 31;
        *(uint4*)(zH + ((size_t)sblk * 32768 + row0 + row) * 32 + off) = v;
    }
    __syncthreads();
#pragma unroll
    for (int ci = 0; ci < 4; ++ci) {
#pragma unroll
        for (int si = 0; si < 4; ++si) {
            float v0 = acc[ci][si][0] + bv[ci].x;
            float v1 = acc[ci][si][1] + bv[ci].y;
            float v2 = acc[ci][si][2] + bv[ci].z;
            float v3 = acc[ci][si][3] + bv[ci].w;
            unsigned h0 = pack2h(v0, v1);
            unsigned h1 = pack2h(v2, v3);
            unsigned l0 = pack2h(v0 - f16lo(h0), v1 - f16hi(h0));
            unsigned l1 = pack2h(v2 - f16lo(h1), v3 - f16hi(h1));
            int row = wr * 64 + si * 16 + m;
            int col = wc * 64 + ci * 16 + g * 4;
            *(uint2*)(sh + (size_t)row * 132 + col) = (uint2){l0, l1};
        }
    }
    __syncthreads();
#pragma unroll
    for (int i = 0; i < 8; ++i) {
        int idx = i * 256 + t;
        int row = idx >> 4, c16 = idx & 15;
        uint4 v = *(const uint4*)(sh + (size_t)row * 132 + c16 * 8);
        int col = cog * 128 + c16 * 8;
        int sblk = col >> 5, off = col & 31;
        *(uint4*)(zL + ((size_t)sblk * 32768 + row0 + row) * 32 + off) = v;
    }
}

// ---- all halo zeroing in one dispatch --------------------------------------
__global__ __launch_bounds__(256) void k_halo_all(
    unsigned short* a1, unsigned short* a2, unsigned short* a3,
    unsigned short* zq, unsigned short* d1)
{
    unsigned short* buf; int Hp, Wp, PS;
    switch (blockIdx.z) {
        case 0: buf = a1; Hp = 258; Wp = 258; PS = 64; break;
        case 1: buf = a2; Hp = 130; Wp = 130; PS = 64; break;
        case 2: buf = a3; Hp = 66; Wp = 66; PS = 64; break;
        case 3: buf = zq; Hp = 66; Wp = 66; PS = 512; break;
        default: buf = d1; Hp = 66; Wp = 66; PS = 64; break;
    }
    int per = 2 * Wp + 2 * (Hp - 2);
    int chunks = PS >> 3;
    int total = per * chunks;
    int n = blockIdx.y;
    for (int i = blockIdx.x * 256 + threadIdx.x; i < total; i += gridDim.x * 256) {
        int pix = i / chunks, c = i - pix * chunks;
        int h, w;
        if (pix < Wp) { h = 0; w = pix; }
        else if (pix < 2 * Wp) { h = Hp - 1; w = pix - Wp; }
        else { int q = pix - 2 * Wp; h = 1 + (q >> 1); w = (q & 1) ? (Wp - 1) : 0; }
        uint4 zz = {0, 0, 0, 0};
        *(uint4*)(buf + (((size_t)n * Hp + h) * Wp + w) * PS + c * 8) = zz;
    }
}

// ---- weight/codebook prep helpers ------------------------------------------
__device__ inline void prep_conv_dev(const float* __restrict__ w,
    unsigned short* __restrict__ o, int Cout, int Cin, int T, int CIC, int idx)
{
    if (idx >= Cout * Cin * T) return;
    int tap = idx % T; int r = idx / T; int ci = r % Cin; int co = r / Cin;
    int chunk = ci / CIC, cil = ci % CIC;
    int k = chunk * (T * CIC) + tap * CIC + cil;
    int s = k >> 5, g = (k >> 3) & 3, j = k & 7;
    o[((size_t)(s * 4 + g) * Cout + co) * 8 + j] = (unsigned short)bf16rne(w[idx]);
}

__device__ inline void prep_wT_dev(const float* __restrict__ w,
    unsigned short* __restrict__ o, int idx)
{
    if (idx >= 65536) return;
    int ci = idx & 63; int r = idx >> 6;
    int jw = r & 1; r >>= 1;
    int jh = r & 1; r >>= 1;
    int co = r & 63; r >>= 6;
    int pw = r & 1; int ph = (r >> 1) & 1;
    int kh = (1 - ph) + 2 * (1 - jh);
    int kw = (1 - pw) + 2 * (1 - jw);
    int k = (jh * 2 + jw) * 64 + ci;
    int s = k >> 5, g = (k >> 3) & 3, j = k & 7;
    o[(size_t)(ph * 2 + pw) * 16384 + ((size_t)(s * 4 + g) * 64 + co) * 8 + j] =
        (unsigned short)bf16rne(w[((ci * 64 + co) * 4 + kh) * 4 + kw]);
}

// ---- all weight/cb/cn2 prep in one dispatch: grid (1152, 8) ----------------
__global__ __launch_bounds__(256) void k_prep_all(
    const float* __restrict__ enc_w2, const float* __restrict__ enc_w3,
    const float* __restrict__ enc_w4, const float* __restrict__ dec_w1,
    const float* __restrict__ tw1, const float* __restrict__ tw2,
    const float* __restrict__ cb,
    unsigned short* __restrict__ wA2, unsigned short* __restrict__ wA3,
    unsigned short* __restrict__ wB1, unsigned short* __restrict__ wB2,
    unsigned short* __restrict__ wC1, unsigned short* __restrict__ wC2,
    unsigned short* __restrict__ cbF,
    float* __restrict__ cn2)
{
    int idx = blockIdx.x * 256 + threadIdx.x;
    switch (blockIdx.y) {
    case 0: prep_conv_dev(enc_w2, wA2, 64, 64, 16, 64, idx); break;
    case 1: prep_conv_dev(enc_w3, wA3, 64, 64, 16, 64, idx); break;
    case 2: prep_conv_dev(enc_w4, wB1, 512, 64, 9, 64, idx); break;
    case 3: prep_conv_dev(dec_w1, wB2, 64, 512, 9, 64, idx); break;
    case 4: prep_wT_dev(tw1, wC1, idx); break;
    case 5: prep_wT_dev(tw2, wC2, idx); break;
    case 6: {
        if (idx < 262144) {
            int c = idx & 511, k = idx >> 9;
            int cblk = k >> 7, kl = k & 127, s = c >> 5, g = (c >> 3) & 3, j = c & 7;
            size_t off = ((((size_t)cblk * 16 + s) * 4 + g) * 128 + kl) * 8 + j;
            cbF[off] = f16bits(cb[idx]);
        }
    } break;
    default: {
        int code = blockIdx.x * 4 + (threadIdx.x >> 6);
        if (code < 512) {
            int l = threadIdx.x & 63;
            float s = 0.f;
#pragma unroll
            for (int i = 0; i < 8; ++i) {
                float v = cb[code * 512 + l + i * 64];
                s = fmaf(v, v, s);
            }
#pragma unroll
            for (int off = 32; off > 0; off >>= 1) s += __shfl_xor(s, off);
            if (l == 0) cn2[code] = 0.5f * s;
        }
    } break;
    }
}

// ---- enc conv1: Cin=1, 4x4 s2 p1, ReLU -> bf16 NHWC padded ----------------
// Weights/bias in SGPRs (lane-uniform global reads). LDS-transpose epilogue:
// contiguous 32KB row stored as lane-consecutive uint4 in two 128-px passes.
__global__ __launch_bounds__(256) void k_conv1(const float* __restrict__ x,
    const float* __restrict__ w, const float* __restrict__ b, unsigned short* __restrict__ out)
{
    __shared__ __align__(16) unsigned short sh[128 * 132];
    int t = threadIdx.x;
    int oh = blockIdx.x;
    int n = blockIdx.y;
    int ow = t;
    const float* xn = x + (size_t)n * 262144;
    float xv[16];
#pragma unroll
    for (int kh = 0; kh < 4; ++kh) {
        int ih = 2 * oh - 1 + kh;
        bool rok = (unsigned)ih < 512u;
        int ihc = min(max(ih, 0), 511);
#pragma unroll
        for (int kw = 0; kw < 4; ++kw) {
            int iw = 2 * ow - 1 + kw;
            bool ok = rok && ((unsigned)iw < 512u);
            int iwc = min(max(iw, 0), 511);
            float v = xn[ihc * 512 + iwc];
            xv[kh * 4 + kw] = ok ? v : 0.f;
        }
    }
    unsigned uo[32];
#pragma unroll
    for (int co2 = 0; co2 < 32; ++co2) {
        float a0 = b[2 * co2], a1 = b[2 * co2 + 1];
#pragma unroll
        for (int q = 0; q < 16; ++q) {
            a0 = fmaf(xv[q], w[(2 * co2) * 16 + q], a0);
            a1 = fmaf(xv[q], w[(2 * co2 + 1) * 16 + q], a1);
        }
        uo[co2] = pack2(fmaxf(a0, 0.f), fmaxf(a1, 0.f));
    }
    unsigned short* rowbase = out + (((size_t)n * 258 + oh + 1) * 258 + 1) * 64;
#pragma unroll
    for (int pass = 0; pass < 2; ++pass) {
        if (pass) __syncthreads();               // protect pass-0 reads
        if ((t >> 7) == pass) {
            int p = t & 127;
            unsigned short* rowp = sh + (size_t)p * 132;
#pragma unroll
            for (int i = 0; i < 8; ++i) {
                uint4 st = {uo[4 * i], uo[4 * i + 1], uo[4 * i + 2], uo[4 * i + 3]};
                *(uint4*)(rowp + i * 8) = st;
            }
        }
        __syncthreads();
        unsigned short* gbase = rowbase + (size_t)pass * 8192;
#pragma unroll
        for (int i = 0; i < 4; ++i) {
            int s = i * 256 + t;                 // lane-consecutive slots
            int p = s >> 3, c = s & 7;
            uint4 v = *(const uint4*)(sh + (size_t)p * 132 + c * 8);
            *(uint4*)(gbase + (size_t)s * 8) = v;
        }
    }
}

__device__ inline bool better_sc(float av, int ai, float bv, int bi) {
    return av > bv || (av == bv && ai < bi);
}

// ---- VQ approx GEMM pass-1: fp16 single-term, top-2 per 128-code block -----
// R17 form: LDS staging with DBUF half-chunks (8 chunks x 2 K-steps,
// 2 x 10240-short buffers); stage(c+1) before compute(c), one barrier/chunk.
// Top-2 via single-compare branchless merges (ties resolved by pass-2).
__global__ __launch_bounds__(256) void k_vqgemm(
    const unsigned short* __restrict__ zH, const unsigned short* __restrict__ cbF,
    const float* __restrict__ cn2, int* __restrict__ candI)
{
    __shared__ __align__(16) unsigned short shA[20480];  // 2 bufs x (2 steps x 640 slots x 8)
    int t = threadIdx.x, lane = t & 63, wv = t >> 6;
    int wc = wv & 1, wr = wv >> 1;
    int m = lane & 15, g = lane >> 4;
    int L = blockIdx.x;
    int xcd = L & 7, kk = L >> 3;
    int cblk = kk & 3;
    int row0 = ((kk >> 2) + xcd * 32) * 128;

    f32x4_t acc[4][4];
#pragma unroll
    for (int a = 0; a < 4; ++a)
#pragma unroll
        for (int b = 0; b < 4; ++b) acc[a][b] = (f32x4_t){0.f, 0.f, 0.f, 0.f};

    const uint4* bF = (const uint4*)cbF + (size_t)cblk * 8192;

    auto stage = [&](int c, int bi) {
        unsigned short* dst = shA + (size_t)bi * 10240;
        for (int q = t; q < 1280; q += 256) {
            int ss = q / 640, rest = q - ss * 640;
            int r = rest / 5, seg = rest - r * 5;
            int s = c * 2 + ss;
            gl_lds16(zH + ((size_t)s * 32768 + row0 + r) * 32 + (seg & 3) * 8,
                     dst + (size_t)q * 8);
        }
    };

    stage(0, 0);
    __syncthreads();
    for (int c = 0; c < 8; ++c) {
        if (c + 1 < 8) stage(c + 1, (c + 1) & 1);
        const unsigned short* buf = shA + (size_t)(c & 1) * 10240;
#pragma unroll
        for (int ss = 0; ss < 2; ++ss) {
            int s = c * 2 + ss;
            Frag16 B[4];
#pragma unroll
            for (int ni = 0; ni < 4; ++ni)
                B[ni].u = bF[(s * 4 + g) * 128 + wc * 64 + ni * 16 + m];
#pragma unroll
            for (int mi = 0; mi < 4; ++mi) {
                Frag16 A;
                A.u = *(const uint4*)(buf + (size_t)(ss * 5120 + (wr * 64 + mi * 16 + m) * 40 + g * 8));
#pragma unroll
                for (int ni = 0; ni < 4; ++ni)
                    acc[mi][ni] = mfma16h(A.h, B[ni].h, acc[mi][ni]);
            }
        }
        if (c + 1 < 8) __syncthreads();
    }
    // argmax scratch aliases into buffer0 region (last read at chunk 6, which
    // is barrier-separated; chunk 7 compute reads buffer1 only — disjoint).
    float* tV = (float*)shA;                 // [wc2][row128][cand2]
    int*   tI = (int*)(shA + 2048);          // byte off 4096, same shape
    float c2v[4];
#pragma unroll
    for (int ni = 0; ni < 4; ++ni) c2v[ni] = cn2[cblk * 128 + wc * 64 + ni * 16 + m];
    int ixb = cblk * 128 + wc * 64 + m;
#pragma unroll
    for (int mi = 0; mi < 4; ++mi) {
#pragma unroll
        for (int r = 0; r < 4; ++r) {
            float a0 = acc[mi][0][r] - c2v[0];
            float a1 = acc[mi][1][r] - c2v[1];
            float a2 = acc[mi][2][r] - c2v[2];
            float a3 = acc[mi][3][r] - c2v[3];
            // sort pairs then merge (branchless, single compares)
            bool cA = a1 > a0;
            float p1 = cA ? a1 : a0; int pi1 = cA ? ixb + 16 : ixb;
            float p2 = cA ? a0 : a1; int pi2 = cA ? ixb : ixb + 16;
            bool cB = a3 > a2;
            float q1 = cB ? a3 : a2; int qi1 = cB ? ixb + 48 : ixb + 32;
            float q2 = cB ? a2 : a3; int qi2 = cB ? ixb + 32 : ixb + 48;
            bool cC = q1 > p1;
            float v1 = cC ? q1 : p1; int i1 = cC ? qi1 : pi1;
            float sa = cC ? p1 : q1; int sai = cC ? pi1 : qi1;
            float sb = cC ? q2 : p2; int sbi = cC ? qi2 : pi2;
            bool cD = sb > sa;
            float v2 = cD ? sb : sa; int i2 = cD ? sbi : sai;
#pragma unroll
            for (int off = 1; off < 16; off <<= 1) {
                float o1 = __shfl_xor(v1, off); int oi1 = __shfl_xor(i1, off);
                float o2 = __shfl_xor(v2, off); int oi2 = __shfl_xor(i2, off);
                bool c = o1 > v1;
                float w2 = c ? v1 : v2; int w2i = c ? i1 : i2;
                float u2 = c ? o2 : o1; int u2i = c ? oi2 : oi1;
                v1 = c ? o1 : v1; i1 = c ? oi1 : i1;
                bool cc = u2 > w2;
                v2 = cc ? u2 : w2; i2 = cc ? u2i : w2i;
            }
            if (m == 0) {
                int row = wr * 64 + mi * 16 + g * 4 + r;
                tV[(wc * 128 + row) * 2 + 0] = v1; tI[(wc * 128 + row) * 2 + 0] = i1;
                tV[(wc * 128 + row) * 2 + 1] = v2; tI[(wc * 128 + row) * 2 + 1] = i2;
            }
        }
    }
    __syncthreads();
    if (t < 128) {
        float v1 = tV[t * 2], v2 = tV[t * 2 + 1];
        int i1 = tI[t * 2], i2 = tI[t * 2 + 1];
        float o1 = tV[(128 + t) * 2], o2 = tV[(128 + t) * 2 + 1];
        int oi1 = tI[(128 + t) * 2], oi2 = tI[(128 + t) * 2 + 1];
        bool c = o1 > v1;
        float w2 = c ? v1 : v2; int w2i = c ? i1 : i2;
        float u2 = c ? o2 : o1; int u2i = c ? oi2 : oi1;
        v1 = c ? o1 : v1; i1 = c ? oi1 : i1;
        bool cc = u2 > w2;
        v2 = cc ? u2 : w2; i2 = cc ? u2i : w2i;
        candI[((size_t)cblk * 2 + 0) * 32768 + row0 + t] = i1;
        candI[((size_t)cblk * 2 + 1) * 32768 + row0 + t] = i2;
    }
}

// ---- VQ pass-2: wave-per-row exact fp32 rescore + fused z_q gather ---------
__global__ __launch_bounds__(256) void k_vqfinal(
    const unsigned short* __restrict__ zH, const unsigned short* __restrict__ zL,
    const float* __restrict__ cb, const int* __restrict__ candI,
    unsigned short* __restrict__ zq, float* __restrict__ mind)
{
    int t = threadIdx.x, lane = t & 63, wv = t >> 6;
    int row = blockIdx.x * 4 + wv;
    size_t zoff = ((size_t)(lane >> 2) * 32768 + row) * 32 + (lane & 3) * 8;
    uint4 hu = *(const uint4*)(zH + zoff);
    uint4 lu = *(const uint4*)(zL + zoff);
    float z0 = f16lo(hu.x) + f16lo(lu.x);
    float z1 = f16hi(hu.x) + f16hi(lu.x);
    float z2 = f16lo(hu.y) + f16lo(lu.y);
    float z3 = f16hi(hu.y) + f16hi(lu.y);
    float z4 = f16lo(hu.z) + f16lo(lu.z);
    float z5 = f16hi(hu.z) + f16hi(lu.z);
    float z6 = f16lo(hu.w) + f16lo(lu.w);
    float z7 = f16hi(hu.w) + f16hi(lu.w);
    int mycand = (lane < 8) ? candI[(size_t)lane * 32768 + row] : 0;
    int cands[8];
    float d[8];
#pragma unroll
    for (int s = 0; s < 8; ++s) cands[s] = __shfl(mycand, s);
#pragma unroll
    for (int s = 0; s < 8; ++s) {
        const float* cr = cb + (size_t)cands[s] * 512 + lane * 8;
        float4 c0 = *(const float4*)cr;
        float4 c1 = *(const float4*)(cr + 4);
        float e, dd = 0.f;
        e = z0 - c0.x; dd = fmaf(e, e, dd);
        e = z1 - c0.y; dd = fmaf(e, e, dd);
        e = z2 - c0.z; dd = fmaf(e, e, dd);
        e = z3 - c0.w; dd = fmaf(e, e, dd);
        e = z4 - c1.x; dd = fmaf(e, e, dd);
        e = z5 - c1.y; dd = fmaf(e, e, dd);
        e = z6 - c1.z; dd = fmaf(e, e, dd);
        e = z7 - c1.w; dd = fmaf(e, e, dd);
        d[s] = dd;
    }
#pragma unroll
    for (int off = 1; off < 64; off <<= 1) {
#pragma unroll
        for (int s = 0; s < 8; ++s) d[s] += __shfl_xor(d[s], off);
    }
    float bd = d[0]; int bi_ = cands[0];
#pragma unroll
    for (int s = 1; s < 8; ++s) {
        if (d[s] < bd || (d[s] == bd && cands[s] < bi_)) { bd = d[s]; bi_ = cands[s]; }
    }
    // bd/bi_ identical across all 64 lanes -> fused z_q gather (bf16 NHWC halo)
    {
        int n = row >> 12, hw = row & 4095, h = hw >> 6, w = hw & 63;
        const float* src = cb + (size_t)bi_ * 512 + lane * 8;
        float4 v0 = *(const float4*)src, v1 = *(const float4*)(src + 4);
        uint4 st = {pack2(v0.x, v0.y), pack2(v0.z, v0.w),
                    pack2(v1.x, v1.y), pack2(v1.z, v1.w)};
        *(uint4*)(zq + (((size_t)n * 66 + h + 1) * 66 + (w + 1)) * 512 + lane * 8) = st;
    }
    if (lane == 0) mind[row] = bd;
}

// ---- final conv-transpose 64 -> 1, sigmoid (LDS-staged, fp16 dot2) ---------
// __launch_bounds__(256,4) caps VGPR at 128; #pragma unroll 2 on the c8 loop
// meets the cap without spills. TLP (3 blocks/CU) hides LDS latency.
__global__ __launch_bounds__(256, 4) void k_convt_final2(const unsigned short* __restrict__ xp,
    const float* __restrict__ w, const float* __restrict__ b, float* __restrict__ out)
{
    __shared__ __align__(16) unsigned short shx[3 * 1040 * 8];
    __shared__ __align__(16) unsigned wp[16][32];
    int t = threadIdx.x, lane = t & 63, wv = t >> 6;
    int bx = blockIdx.x, q = blockIdx.y, n = blockIdx.z;
    int colbase = bx * 128;
#pragma unroll
    for (int i = 0; i < 2; ++i) {
        int qq = t + i * 256;
        int tap = qq >> 5, c2 = qq & 31;
        wp[tap][c2] = pack2h(w[(2 * c2) * 16 + tap], w[(2 * c2 + 1) * 16 + tap]);
    }
    const unsigned short* an = xp + (size_t)n * 258 * 258 * 64;
    for (int u_ = wv; u_ < 51; u_ += 4) {
        int r = u_ / 17, seg = u_ % 17;
        int slot = seg * 64 + lane;
        if (slot < 1040) {
            int p = slot >> 3, uu = slot & 7;
            int su = (uu - p) & 7;
            int row = min(2 * q + r, 257);
            const unsigned short* gsrc = an + ((size_t)row * 258 + colbase + p) * 64 + su * 8;
            gl_lds16(gsrc, shx + ((size_t)(r * 1040 + slot)) * 8);
        }
    }
    __syncthreads();
    int ow = bx * 256 + t;
    int kwA = (ow + 1) & 1;
    int cA = ((ow + 1) >> 1) + 1 - colbase;
    int cB = cA - 1;
    float b0 = b[0];
    float acc0 = b0, acc1 = b0, acc2 = b0, acc3 = b0;
#pragma unroll 2
    for (int c8 = 0; c8 < 8; ++c8) {
        uint4 xr[3][2];
#pragma unroll
        for (int r = 0; r < 3; ++r) {
            xr[r][0] = *(const uint4*)(shx + (size_t)(r * 1040 + cB * 8 + ((c8 + cB) & 7)) * 8);
            xr[r][1] = *(const uint4*)(shx + (size_t)(r * 1040 + cA * 8 + ((c8 + cA) & 7)) * 8);
        }
        uint4 wA[4], wB[4];
#pragma unroll
        for (int kh = 0; kh < 4; ++kh) {
            wA[kh] = *(const uint4*)&wp[kh * 4 + kwA][c8 * 4];
            wB[kh] = *(const uint4*)&wp[kh * 4 + kwA + 2][c8 * 4];
        }
        acc0 = dot8(xr[1][1], wA[0], acc0); acc0 = dot8(xr[1][0], wB[0], acc0);
        acc0 = dot8(xr[0][1], wA[2], acc0); acc0 = dot8(xr[0][0], wB[2], acc0);
        acc1 = dot8(xr[1][1], wA[1], acc1); acc1 = dot8(xr[1][0], wB[1], acc1);
        acc1 = dot8(xr[0][1], wA[3], acc1); acc1 = dot8(xr[0][0], wB[3], acc1);
        acc2 = dot8(xr[2][1], wA[0], acc2); acc2 = dot8(xr[2][0], wB[0], acc2);
        acc2 = dot8(xr[1][1], wA[2], acc2); acc2 = dot8(xr[1][0], wB[2], acc2);
        acc3 = dot8(xr[2][1], wA[1], acc3); acc3 = dot8(xr[2][0], wB[1], acc3);
        acc3 = dot8(xr[1][1], wA[3], acc3); acc3 = dot8(xr[1][0], wB[3], acc3);
    }
    float accs[4] = {acc0, acc1, acc2, acc3};
    float* on = out + (size_t)n * 262144;
#pragma unroll
    for (int ro = 0; ro < 4; ++ro) {
        int oh = 4 * q - 1 + ro;
        if ((unsigned)oh < 512u)
            on[(size_t)oh * 512 + ow] = 1.0f / (1.0f + __expf(-accs[ro]));
    }
}

// ---- finalize loss: single-block reduction over mind[32768] ----------------
__global__ __launch_bounds__(256) void k_loss_final(const float* __restrict__ mind,
    float* __restrict__ out)
{
    __shared__ float redd[4];
    int t = threadIdx.x;
    float s = 0.f;
#pragma unroll 4
    for (int i = 0; i < 32; ++i) {
        float4 v = *(const float4*)(mind + i * 1024 + t * 4);
        s += v.x + v.y + v.z + v.w;
    }
#pragma unroll
    for (int off = 1; off < 64; off <<= 1) s += __shfl_xor(s, off);
    if ((t & 63) == 0) redd[t >> 6] = s;
    __syncthreads();
    if (t == 0)
        out[0] = 1.25f * (redd[0] + redd[1] + redd[2] + redd[3]) * (1.0f / 16777216.0f);
}

// ---------------------------------------------------------------------------
extern "C" void kernel_launch(void* const* d_in, const int* in_sizes, int n_in,
                              void* d_out, int out_size, void* d_ws, size_t ws_size,
                              hipStream_t stream)
{
    const float* x      = (const float*)d_in[0];
    const float* enc_w1 = (const float*)d_in[1];
    const float* enc_b1 = (const float*)d_in[2];
    const float* enc_w2 = (const float*)d_in[3];
    const float* enc_b2 = (const float*)d_in[4];
    const float* enc_w3 = (const float*)d_in[5];
    const float* enc_b3 = (const float*)d_in[6];
    const float* enc_w4 = (const float*)d_in[7];
    const float* enc_b4 = (const float*)d_in[8];
    const float* cb     = (const float*)d_in[9];
    const float* dec_w1 = (const float*)d_in[10];
    const float* dec_b1 = (const float*)d_in[11];
    const float* tw1    = (const float*)d_in[12];
    const float* tb1    = (const float*)d_in[13];
    const float* tw2    = (const float*)d_in[14];
    const float* tb2    = (const float*)d_in[15];
    const float* tw3    = (const float*)d_in[16];
    const float* tb3    = (const float*)d_in[17];
    float* out = (float*)d_out;

    unsigned short* a1 = (unsigned short*)d_ws;        // 8*258*258*64
    unsigned short* a2 = a1 + 34076672;                // 8*130*130*64
    unsigned short* a3 = a2 + 8652800;                 // 8*66*66*64
    unsigned short* zH = a3 + 2230272;                 // 16*32768*32 (fp16)
    unsigned short* zL = zH + 16777216;                // 16*32768*32 (fp16)
    unsigned short* zq = zL + 16777216;                // 8*66*66*512
    unsigned short* d1 = zq + 17842176;                // 8*66*66*64
    unsigned short* wA2 = d1 + 2230272;                // 65536
    unsigned short* wA3 = wA2 + 65536;
    unsigned short* wB1 = wA3 + 65536;                 // 294912
    unsigned short* wB2 = wB1 + 294912;                // 294912
    unsigned short* wC1 = wB2 + 294912;                // 65536
    unsigned short* wC2 = wC1 + 65536;                 // 65536
    unsigned short* cbF = wC2 + 65536;                 // 262144 (fp16 frag)
    float* cn2 = (float*)(cbF + 262144);               // 512
    int*   candI = (int*)(cn2 + 512);                  // 8*32768
    float* mind = (float*)(candI + 262144);            // 32768
    float* pf = (float*)zH;                            // dec1 partials (zH dead after vqfinal)

    // consolidated halos + preps
    k_halo_all<<<dim3(65, 8, 5), 256, 0, stream>>>(a1, a2, a3, zq, d1);
    k_prep_all<<<dim3(1152, 8), 256, 0, stream>>>(
        enc_w2, enc_w3, enc_w4, dec_w1, tw1, tw2, cb,
        wA2, wA3, wB1, wB2, wC1, wC2, cbF, cn2);

    // pipeline
    k_conv1<<<dim3(256, 8), 256, 0, stream>>>(x, enc_w1, enc_b1, a1);
    k_enc2w<<<dim3(128, 8), 256, 0, stream>>>(a1, wA2, enc_b2, a2);
    conv_mfma<4, 4, 2, 64, 32, 1, 0, 0><<<dim3(2, 64, 8), 256, 0, stream>>>(
        a2, wA3, enc_b3, a3, 130, 130, 64, 1, 64, 1, 66, 66, 1);
    k_enc4<<<1024, 256, 0, stream>>>(a3, wB1, enc_b4, zH, zL);
    k_vqgemm<<<1024, 256, 0, stream>>>(zH, cbF, cn2, candI);
    k_vqfinal<<<8192, 256, 0, stream>>>(zH, zL, cb, candI, zq, mind);
    // dec1 K-split x2, single-buffer LDS (25344B) -> 4 blocks/CU resident
    conv_mfma<3, 3, 1, 64, 64, 2, 4, 0><<<dim3(2, 64, 8), 256, 0, stream>>>(
        zq, wB2, dec_b1, pf, 66, 66, 512, 4, 64, 1, 66, 66, 0);
    k_dec1red<<<1024, 256, 0, stream>>>(pf, dec_b1, d1);
    k_convtf<0><<<dim3(1, 128, 8), 256, 0, stream>>>(d1, wC1, tb1, a2, 66, 66, 130, 130);
    k_convtf<3><<<dim3(2, 256, 8), 256, 0, stream>>>(a2, wC2, tb2, a1, 130, 130, 258, 258);
    k_convt_final2<<<dim3(2, 129, 8), 256, 0, stream>>>(a1, tw3, tb3, out);
    k_loss_final<<<1, 256, 0, stream>>>(mind, out + 2097152);
}

// Round 17
// 379.474 us; speedup vs baseline: 1.0199x; 1.0199x over previous
//
#include <hip/hip_runtime.h>
#include <math.h>

// ---------------------------------------------------------------------------
// VQ-VAE forward, bf16-MFMA. Round 30: eliminate the zq tensor (35.7MB store
// + ~104MB staged re-read). vqfinal now writes only idx (int, halo'd [66][66],
// code 512 = reserved zero row); dec1 (conv_mfma OUTM==5) gathers its stage
// chunks from a 525KB L2-resident bf16 codebook cbB[513][512] via per-pixel
// idx lookup — gl_lds16's global source is per-lane so the gather drops into
// the existing stage. Values bit-identical (bf16rne both paths).
// Everything else = R27/R29 (~385us plateau).
// ---------------------------------------------------------------------------

typedef __bf16 bf16x8_t __attribute__((ext_vector_type(8)));
typedef _Float16 f16x8_t __attribute__((ext_vector_type(8)));
typedef float f32x4_t __attribute__((ext_vector_type(4)));
typedef _Float16 h2_t __attribute__((ext_vector_type(2)));

union FragU { uint4 u; bf16x8_t b; };
union Frag16 { uint4 u; f16x8_t h; };

__device__ inline f32x4_t mfma16(bf16x8_t a, bf16x8_t b, f32x4_t c) {
    return __builtin_amdgcn_mfma_f32_16x16x32_bf16(a, b, c, 0, 0, 0);
}
__device__ inline f32x4_t mfma16h(f16x8_t a, f16x8_t b, f32x4_t c) {
    return __builtin_amdgcn_mfma_f32_16x16x32_f16(a, b, c, 0, 0, 0);
}

__device__ inline void gl_lds16(const void* g, void* l) {
    __builtin_amdgcn_global_load_lds((const __attribute__((address_space(1))) void*)g,
                                     (__attribute__((address_space(3))) void*)l, 16, 0, 0);
}

__device__ inline unsigned bf16rne(float f) {
    unsigned u = __float_as_uint(f);
    u += 0x7FFFu + ((u >> 16) & 1u);
    return u >> 16;
}
__device__ inline unsigned pack2(float lo, float hi) {
    return bf16rne(lo) | (bf16rne(hi) << 16);
}
__device__ inline unsigned pack2h(float lo, float hi) {
    union { h2_t h; unsigned u; } r;
    r.h[0] = (_Float16)lo; r.h[1] = (_Float16)hi;
    return r.u;
}
__device__ inline unsigned short f16bits(float v) {
    union { _Float16 h; unsigned short s; } x; x.h = (_Float16)v; return x.s;
}
__device__ inline float f16lo(unsigned u) {
    union { unsigned u; h2_t h; } x; x.u = u; return (float)x.h[0];
}
__device__ inline float f16hi(unsigned u) {
    union { unsigned u; h2_t h; } x; x.u = u; return (float)x.h[1];
}
__device__ inline float bl(unsigned u) { return __uint_as_float(u << 16); }
__device__ inline float bh(unsigned u) { return __uint_as_float(u & 0xffff0000u); }

#if defined(__has_builtin)
#if __has_builtin(__builtin_amdgcn_fdot2)
#define HAS_FDOT2 1
#endif
#endif

__device__ inline float dot2h(unsigned x, unsigned w, float a) {
#ifdef HAS_FDOT2
    union { unsigned u; h2_t h; } ax, bw;
    ax.u = x; bw.u = w;
    return __builtin_amdgcn_fdot2(ax.h, bw.h, a, false);
#else
    union { unsigned u; _Float16 h[2]; } ax, bw;
    ax.u = x; bw.u = w;
    a = fmaf((float)ax.h[0], (float)bw.h[0], a);
    return fmaf((float)ax.h[1], (float)bw.h[1], a);
#endif
}
__device__ inline float dot8(uint4 x, uint4 w, float a) {
    a = dot2h(x.x, w.x, a); a = dot2h(x.y, w.y, a);
    a = dot2h(x.z, w.z, a); a = dot2h(x.w, w.w, a);
    return a;
}

// ---- generic implicit-GEMM conv (enc3, dec1) -------------------------------
// DBUF=1: double-buffered LDS; stage(ch+1) issued before compute(ch).
// OUTM==4: K-split partial mode — blockIdx.x selects the chunk-half, output
// is raw fp32 acc (no bias/relu) to [khalf][nb][4096pix][64ch].
// OUTM==5: K-split partial + GATHER stage: in = cbB[513][512] bf16 codebook,
// idxb = halo'd [66][66] per-n code map (512 -> zero row).
template<int NR, int KW_, int SW, int CIC, int SPT, int NT, int OUTM, int DBUF>
__global__ __launch_bounds__(256) void conv_mfma(
    const unsigned short* __restrict__ in, const unsigned short* __restrict__ wp,
    const float* __restrict__ bias, void* __restrict__ outp,
    int Hp, int Wp, int PS, int nchunks, int Cout, int ncog,
    int Hpo, int Wpo, int relu, const int* __restrict__ idxb)
{
    constexpr int W_ST = SW * (SPT - 1) + KW_;
    constexpr int SLOTS_PP = CIC / 8;
    constexpr int ROW_SLOTS = W_ST * SLOTS_PP;
    constexpr int SEGS = (ROW_SLOTS + 63) / 64;
    constexpr int KT = NR * KW_;
    constexpr int CSTEPS = CIC / 32;
    constexpr int BUFSZ = NR * W_ST * CIC;
    __shared__ __align__(16) unsigned short sh[(DBUF ? 2 : 1) * BUFSZ];

    int t = threadIdx.x, lane = t & 63, wv = t >> 6;
    int bx = blockIdx.x;
    int owt, khalf;
    if constexpr (OUTM >= 4) { khalf = bx; owt = 0; }
    else { khalf = 0; owt = bx; }
    int ch0 = khalf * nchunks;
    int ohg = blockIdx.y;
    int bz = blockIdx.z; int nb = bz / ncog; int cog = bz % ncog;
    int ow0 = owt * SPT;
    int row0 = SW * ohg;
    int col0 = SW * ow0;
    int coh = wv & 1;
    int sph = wv >> 1;
    int m = lane & 15, g = lane >> 4;

    f32x4_t acc[2][NT];
#pragma unroll
    for (int a = 0; a < 2; ++a)
#pragma unroll
        for (int u2 = 0; u2 < NT; ++u2) acc[a][u2] = (f32x4_t){0.f, 0.f, 0.f, 0.f};

    auto stage = [&](int ch, unsigned short* buf) {
        for (int u_ = wv; u_ < NR * SEGS; u_ += 4) {
            int r = u_ / SEGS, seg = u_ - r * SEGS;
            int slot = seg * 64 + lane;
            int p = slot / SLOTS_PP;
            int uu = slot & (SLOTS_PP - 1);
            if (p < W_ST) {
                int su = (uu - (p & 7)) & (SLOTS_PP - 1);
                const unsigned short* gsrc;
                if constexpr (OUTM == 5) {
                    int code = idxb[((size_t)nb * Hp + (row0 + r)) * Wp + (col0 + p)];
                    gsrc = in + (size_t)code * 512 + (ch0 + ch) * CIC + su * 8;
                } else {
                    gsrc = in +
                        (((size_t)nb * Hp + (row0 + r)) * Wp + (col0 + p)) * PS + (ch0 + ch) * CIC + su * 8;
                }
                unsigned short* ldst = buf + ((size_t)(r * ROW_SLOTS + seg * 64 + lane)) * 8;
                gl_lds16(gsrc, ldst);
            }
        }
    };

    auto compute = [&](int ch, const unsigned short* buf) {
        int sbase = (ch0 + ch) * (KT * CSTEPS);
#pragma unroll
        for (int tap = 0; tap < KT; ++tap) {
            const int r_l = tap / KW_, kwp = tap % KW_;
#pragma unroll
            for (int cs = 0; cs < CSTEPS; ++cs) {
                int s = sbase + tap * CSTEPS + cs;
                const uint4* wr = (const uint4*)wp + (size_t)(s * 4 + g) * Cout + cog * 64 + coh * 32 + m;
                FragU a0, a1;
                a0.u = wr[0];
                a1.u = wr[16];
#pragma unroll
                for (int u2 = 0; u2 < NT; ++u2) {
                    int sp_l = sph * (SPT / 2) + u2 * 16 + m;
                    int p = SW * sp_l + kwp;
                    int off = (cs * 32 + g * 8 + ((p & 7) << 3)) & (CIC - 1);
                    FragU bb;
                    bb.u = *(const uint4*)(buf + (size_t)(r_l * W_ST + p) * CIC + off);
                    acc[0][u2] = mfma16(a0.b, bb.b, acc[0][u2]);
                    acc[1][u2] = mfma16(a1.b, bb.b, acc[1][u2]);
                }
            }
        }
    };

    stage(0, sh);
    __syncthreads();
    for (int ch = 0; ch < nchunks; ++ch) {
        if constexpr (DBUF != 0) {
            if (ch + 1 < nchunks) stage(ch + 1, sh + (size_t)((ch + 1) & 1) * BUFSZ);
        }
        compute(ch, DBUF ? (sh + (size_t)(ch & 1) * BUFSZ) : sh);
        if (ch + 1 < nchunks) {
            if constexpr (DBUF == 0) {
                __syncthreads();
                stage(ch + 1, sh);
            }
            __syncthreads();
        }
    }
    if constexpr (OUTM >= 4) {
        float* ob = (float*)outp;
#pragma unroll
        for (int a = 0; a < 2; ++a) {
#pragma unroll
            for (int u2 = 0; u2 < NT; ++u2) {
                int ow = ow0 + sph * (SPT / 2) + u2 * 16 + m;
                float4 st = {acc[a][u2][0], acc[a][u2][1], acc[a][u2][2], acc[a][u2][3]};
                *(float4*)(ob + ((((size_t)khalf * 8 + nb) * 4096 + ohg * 64 + ow) * 64
                          + (coh * 32 + a * 16 + g * 4))) = st;
            }
        }
    } else {
#pragma unroll
        for (int a = 0; a < 2; ++a) {
            int co = cog * 64 + coh * 32 + a * 16 + g * 4;
            float4 bv = *(const float4*)(bias + co);
#pragma unroll
            for (int u2 = 0; u2 < NT; ++u2) {
                int ow = ow0 + sph * (SPT / 2) + u2 * 16 + m;
                float v0 = acc[a][u2][0] + bv.x;
                float v1 = acc[a][u2][1] + bv.y;
                float v2 = acc[a][u2][2] + bv.z;
                float v3 = acc[a][u2][3] + bv.w;
                if (relu) {
                    v0 = fmaxf(v0, 0.f); v1 = fmaxf(v1, 0.f);
                    v2 = fmaxf(v2, 0.f); v3 = fmaxf(v3, 0.f);
                }
                unsigned short* ob = (unsigned short*)outp;
                uint2 st;
                if constexpr (OUTM == 3) st = (uint2){pack2h(v0, v1), pack2h(v2, v3)};
                else                     st = (uint2){pack2(v0, v1), pack2(v2, v3)};
                *(uint2*)(ob + (((size_t)nb * Hpo + ohg + 1) * Wpo + (ow + 1)) * 64
                          + (coh * 32 + a * 16 + g * 4)) = st;
            }
        }
    }
}

// ---- dec1 K-split reduce: sum halves + bias + ReLU -> bf16 d1 halo ---------
__global__ __launch_bounds__(256) void k_dec1red(const float* __restrict__ pf,
    const float* __restrict__ bias, unsigned short* __restrict__ d1)
{
    int idx = blockIdx.x * 256 + threadIdx.x;     // 262144 total
    int c8 = idx & 7;
    int rest = idx >> 3;                          // n*4096 + pix
    int pix = rest & 4095, n = rest >> 12;
    const float* p0 = pf + (size_t)rest * 64 + c8 * 8;
    const float* p1 = p0 + (size_t)32768 * 64;
    float4 a0 = *(const float4*)p0, a1 = *(const float4*)(p0 + 4);
    float4 b0 = *(const float4*)p1, b1 = *(const float4*)(p1 + 4);
    float4 s0 = *(const float4*)(bias + c8 * 8);
    float4 s1 = *(const float4*)(bias + c8 * 8 + 4);
    float v0 = fmaxf(a0.x + b0.x + s0.x, 0.f);
    float v1 = fmaxf(a0.y + b0.y + s0.y, 0.f);
    float v2 = fmaxf(a0.z + b0.z + s0.z, 0.f);
    float v3 = fmaxf(a0.w + b0.w + s0.w, 0.f);
    float v4 = fmaxf(a1.x + b1.x + s1.x, 0.f);
    float v5 = fmaxf(a1.y + b1.y + s1.y, 0.f);
    float v6 = fmaxf(a1.z + b1.z + s1.z, 0.f);
    float v7 = fmaxf(a1.w + b1.w + s1.w, 0.f);
    uint4 st = {pack2(v0, v1), pack2(v2, v3), pack2(v4, v5), pack2(v6, v7)};
    int h = pix >> 6, w = pix & 63;
    *(uint4*)(d1 + ((size_t)(n * 66 + h + 1) * 66 + (w + 1)) * 64 + c8 * 8) = st;
}

// ---- enc2: 4x4 s2 conv 64->64, full-row blocks (64co x 128sp) --------------
__global__ __launch_bounds__(256) void k_enc2w(
    const unsigned short* __restrict__ in, const unsigned short* __restrict__ wp,
    const float* __restrict__ bias, unsigned short* __restrict__ out)
{
    __shared__ __align__(16) unsigned short sh[16512];   // 258 px x 64 ch
    int t = threadIdx.x, lane = t & 63, wv = t >> 6;
    int m = lane & 15, g = lane >> 4;
    int ohg = blockIdx.x, n = blockIdx.y;

    f32x4_t acc[4][2];
#pragma unroll
    for (int a = 0; a < 4; ++a)
#pragma unroll
        for (int u2 = 0; u2 < 2; ++u2) acc[a][u2] = (f32x4_t){0.f, 0.f, 0.f, 0.f};

    const uint4* wp4 = (const uint4*)wp;
#pragma unroll
    for (int kh = 0; kh < 4; ++kh) {
        if (kh) __syncthreads();
        const unsigned short* rowp = in + ((size_t)(n * 258 + 2 * ohg + kh) * 258) * 64;
        for (int q = t; q < 2064; q += 256) {
            int p = q >> 3, uu = q & 7;
            int su = (uu - ((p >> 1) & 7)) & 7;
            gl_lds16(rowp + (size_t)p * 64 + su * 8, sh + (size_t)q * 8);
        }
        __syncthreads();
#pragma unroll
        for (int kwp = 0; kwp < 4; ++kwp) {
#pragma unroll
            for (int cs = 0; cs < 2; ++cs) {
                int s = (kh * 4 + kwp) * 2 + cs;
                const uint4* wr = wp4 + (size_t)(s * 4 + g) * 64 + m;
                FragU A[4];
#pragma unroll
                for (int a = 0; a < 4; ++a) A[a].u = wr[a * 16];
#pragma unroll
                for (int u2 = 0; u2 < 2; ++u2) {
                    int sp_l = wv * 32 + u2 * 16 + m;
                    int p = 2 * sp_l + kwp;
                    int rot = (sp_l + (kwp >> 1)) & 7;
                    int off = (cs * 32 + g * 8 + rot * 8) & 63;
                    FragU B;
                    B.u = *(const uint4*)(sh + (size_t)p * 64 + off);
#pragma unroll
                    for (int a = 0; a < 4; ++a)
                        acc[a][u2] = mfma16(A[a].b, B.b, acc[a][u2]);
                }
            }
        }
    }
#pragma unroll
    for (int a = 0; a < 4; ++a) {
        float4 bv = *(const float4*)(bias + a * 16 + g * 4);
#pragma unroll
        for (int u2 = 0; u2 < 2; ++u2) {
            int ow = wv * 32 + u2 * 16 + m;
            float v0 = fmaxf(acc[a][u2][0] + bv.x, 0.f);
            float v1 = fmaxf(acc[a][u2][1] + bv.y, 0.f);
            float v2 = fmaxf(acc[a][u2][2] + bv.z, 0.f);
            float v3 = fmaxf(acc[a][u2][3] + bv.w, 0.f);
            uint2 st = {pack2(v0, v1), pack2(v2, v3)};
            *(uint2*)(out + ((size_t)(n * 130 + ohg + 1) * 130 + ow + 1) * 64
                      + a * 16 + g * 4) = st;
        }
    }
}

// ---- fused conv-transpose 4x4 s2: one output-row (ph) per block ------------
// ph-split for TLP — block stages 2 input rows (17KB LDS), waves split
// (pw, u2-half), acc[4][2]. Epilogue: contiguous-row store ([128][68] alias).
template<int OUTM>
__global__ __launch_bounds__(256) void k_convtf(
    const unsigned short* __restrict__ in, const unsigned short* __restrict__ wp,
    const float* __restrict__ bias, unsigned short* __restrict__ out,
    int Hpi, int Wpi, int Hpo, int Wpo)
{
    __shared__ __align__(16) unsigned short sh[8704];    // 2x528x8=8448 stage; alias [128][68]
    int t = threadIdx.x, lane = t & 63, wv = t >> 6;
    int m = lane & 15, g = lane >> 4;
    int pw = wv & 1, u2h = wv >> 1;
    int owt = blockIdx.x;
    int by = blockIdx.y; int ohg = by >> 1, ph = by & 1;
    int n = blockIdx.z;
    int col0 = owt * 64;

    const unsigned short* an = in + ((size_t)(n * Hpi + ohg + ph) * Wpi + col0) * 64;
    for (int q = t; q < 1056; q += 256) {
        int r = q / 528, rest = q - r * 528;
        int p = rest >> 3, uu = rest & 7;
        int su = (uu - (p & 7)) & 7;
        gl_lds16(an + ((size_t)r * Wpi + p) * 64 + su * 8, sh + (size_t)q * 8);
    }
    f32x4_t acc[4][2];
#pragma unroll
    for (int a = 0; a < 4; ++a)
#pragma unroll
        for (int u2i = 0; u2i < 2; ++u2i) acc[a][u2i] = (f32x4_t){0.f, 0.f, 0.f, 0.f};
    __syncthreads();

    const uint4* ws4 = (const uint4*)(wp + (size_t)(ph * 2 + pw) * 16384);
#pragma unroll
    for (int jh = 0; jh < 2; ++jh) {
#pragma unroll
        for (int jw = 0; jw < 2; ++jw) {
#pragma unroll
            for (int cs = 0; cs < 2; ++cs) {
                int s = (jh * 2 + jw) * 2 + cs;
                const uint4* wr = ws4 + (size_t)(s * 4 + g) * 64 + m;
                FragU A[4];
#pragma unroll
                for (int a = 0; a < 4; ++a) A[a].u = wr[a * 16];
#pragma unroll
                for (int u2i = 0; u2i < 2; ++u2i) {
                    int u2 = u2h * 2 + u2i;
                    int p = u2 * 16 + m + pw + jw;
                    int off = (cs * 32 + g * 8 + ((p & 7) << 3)) & 63;
                    FragU B;
                    B.u = *(const uint4*)(sh + (size_t)(jh * 528 + p * 8) * 8 + off);
#pragma unroll
                    for (int a = 0; a < 4; ++a)
                        acc[a][u2i] = mfma16(A[a].b, B.b, acc[a][u2i]);
                }
            }
        }
    }
    // epilogue: bias+relu+pack, LDS [128][68] alias, contiguous row store
    unsigned pk[4][2][2];
#pragma unroll
    for (int a = 0; a < 4; ++a) {
        float4 bv = *(const float4*)(bias + a * 16 + g * 4);
#pragma unroll
        for (int u2i = 0; u2i < 2; ++u2i) {
            float v0 = fmaxf(acc[a][u2i][0] + bv.x, 0.f);
            float v1 = fmaxf(acc[a][u2i][1] + bv.y, 0.f);
            float v2 = fmaxf(acc[a][u2i][2] + bv.z, 0.f);
            float v3 = fmaxf(acc[a][u2i][3] + bv.w, 0.f);
            if constexpr (OUTM == 3) { pk[a][u2i][0] = pack2h(v0, v1); pk[a][u2i][1] = pack2h(v2, v3); }
            else                     { pk[a][u2i][0] = pack2(v0, v1);  pk[a][u2i][1] = pack2(v2, v3); }
        }
    }
    __syncthreads();                             // stage reads done before alias
#pragma unroll
    for (int u2i = 0; u2i < 2; ++u2i) {
        int u2 = u2h * 2 + u2i;
        int lp = 2 * (u2 * 16 + m) + pw;         // local pixel 0..127
#pragma unroll
        for (int a = 0; a < 4; ++a)
            *(uint2*)(sh + (size_t)lp * 68 + a * 16 + g * 4) =
                (uint2){pk[a][u2i][0], pk[a][u2i][1]};
    }
    __syncthreads();
    unsigned short* gbase = out + ((size_t)(n * Hpo + 2 * ohg + ph + 1) * Wpo
                          + 2 * col0 + 1) * 64;
#pragma unroll
    for (int i = 0; i < 4; ++i) {
        int s = i * 256 + t;                     // 1024 uint4 slots = 128px x 64ch
        int p = s >> 3, c8 = s & 7;
        uint4 v = *(const uint4*)(sh + (size_t)p * 68 + c8 * 8);
        *(uint4*)(gbase + (size_t)s * 8) = v;
    }
}

// ---- enc4: 3x3 s1 conv 64->512, 128sp x 128co tiles ------------------------
__global__ __launch_bounds__(256) void k_enc4(
    const unsigned short* __restrict__ a3, const unsigned short* __restrict__ wp,
    const float* __restrict__ bias, unsigned short* __restrict__ zH,
    unsigned short* __restrict__ zL)
{
    __shared__ __align__(16) unsigned short sh[16896];
    int t = threadIdx.x, lane = t & 63, wv = t >> 6;
    int wc = wv & 1, wr = wv >> 1;
    int m = lane & 15, g = lane >> 4;
    int L = blockIdx.x;
    int xcd = L & 7, j = L >> 3;
    int cog = j & 3;
    int rt = (j >> 2) + xcd * 32;
    int row0 = rt * 128;
    int n = row0 >> 12;
    int oh0 = (row0 & 4095) >> 6;

    const unsigned short* an = a3 + ((size_t)(n * 66 + oh0) * 66) * 64;
    for (int seg = wv; seg < 33; seg += 4) {
        int slot = seg * 64 + lane;
        if (slot < 2112) {
            int r = slot / 528, rest = slot - r * 528;
            int p = rest >> 3, uu = rest & 7;
            int su = (uu - p) & 7;
            gl_lds16(an + ((size_t)(r * 66 + p)) * 64 + su * 8, sh + (size_t)slot * 8);
        }
    }
    f32x4_t acc[4][4];
#pragma unroll
    for (int a = 0; a < 4; ++a)
#pragma unroll
        for (int b = 0; b < 4; ++b) acc[a][b] = (f32x4_t){0.f, 0.f, 0.f, 0.f};
    __syncthreads();

#pragma unroll
    for (int tap = 0; tap < 9; ++tap) {
        const int kh = tap / 3, kwp = tap % 3;
#pragma unroll
        for (int cs = 0; cs < 2; ++cs) {
            int s = tap * 2 + cs;
            const uint4* wr4 = (const uint4*)wp + (size_t)(s * 4 + g) * 512 + cog * 128 + wc * 64 + m;
            FragU A[4];
#pragma unroll
            for (int ci = 0; ci < 4; ++ci) A[ci].u = wr4[ci * 16];
#pragma unroll
            for (int si = 0; si < 4; ++si) {
                int sp_l = wr * 64 + si * 16 + m;
                int r_l = (sp_l >> 6) + kh;
                int px = (sp_l & 63) + kwp;
                int off = (cs * 4 + g + px) & 7;
                FragU B;
                B.u = *(const uint4*)(sh + ((size_t)(r_l * 528 + px * 8 + off)) * 8);
#pragma unroll
                for (int ci = 0; ci < 4; ++ci)
                    acc[ci][si] = mfma16(A[ci].b, B.b, acc[ci][si]);
            }
        }
    }
    float4 bv[4];
#pragma unroll
    for (int ci = 0; ci < 4; ++ci)
        bv[ci] = *(const float4*)(bias + cog * 128 + wc * 64 + ci * 16 + g * 4);

    __syncthreads();
#pragma unroll
    for (int ci = 0; ci < 4; ++ci) {
#pragma unroll
        for (int si = 0; si < 4; ++si) {
            float v0 = acc[ci][si][0] + bv[ci].x;
            float v1 = acc[ci][si][1] + bv[ci].y;
            float v2 = acc[ci][si][2] + bv[ci].z;
            float v3 = acc[ci][si][3] + bv[ci].w;
            unsigned h0 = pack2h(v0, v1);
            unsigned h1 = pack2h(v2, v3);
            int row = wr * 64 + si * 16 + m;
            int col = wc * 64 + ci * 16 + g * 4;
            *(uint2*)(sh + (size_t)row * 132 + col) = (uint2){h0, h1};
        }
    }
    __syncthreads();
#pragma unroll
    for (int i = 0; i < 8; ++i) {
        int idx = i * 256 + t;
        int row = idx >> 4, c16 = idx & 15;
        uint4 v = *(const uint4*)(sh + (size_t)row * 132 + c16 * 8);
        int col = cog * 128 + c16 * 8;
        int sblk = col >> 5, off = col & 31;
        *(uint4*)(zH + ((size_t)sblk * 32768 + row0 + row) * 32 + off) = v;
    }
    __syncthreads();
#pragma unroll
    for (int ci = 0; ci < 4; ++ci) {
#pragma unroll
        for (int si = 0; si < 4; ++si) {
            float v0 = acc[ci][si][0] + bv[ci].x;
            float v1 = acc[ci][si][1] + bv[ci].y;
            float v2 = acc[ci][si][2] + bv[ci].z;
            float v3 = acc[ci][si][3] + bv[ci].w;
            unsigned h0 = pack2h(v0, v1);
            unsigned h1 = pack2h(v2, v3);
            unsigned l0 = pack2h(v0 - f16lo(h0), v1 - f16hi(h0));
            unsigned l1 = pack2h(v2 - f16lo(h1), v3 - f16hi(h1));
            int row = wr * 64 + si * 16 + m;
            int col = wc * 64 + ci * 16 + g * 4;
            *(uint2*)(sh + (size_t)row * 132 + col) = (uint2){l0, l1};
        }
    }
    __syncthreads();
#pragma unroll
    for (int i = 0; i < 8; ++i) {
        int idx = i * 256 + t;
        int row = idx >> 4, c16 = idx & 15;
        uint4 v = *(const uint4*)(sh + (size_t)row * 132 + c16 * 8);
        int col = cog * 128 + c16 * 8;
        int sblk = col >> 5, off = col & 31;
        *(uint4*)(zL + ((size_t)sblk * 32768 + row0 + row) * 32 + off) = v;
    }
}

// ---- all halo zeroing in one dispatch --------------------------------------
// case 3 now fills the idx map halo with code 512 (the reserved zero row).
__global__ __launch_bounds__(256) void k_halo_all(
    unsigned short* a1, unsigned short* a2, unsigned short* a3,
    int* idxb, unsigned short* d1)
{
    if (blockIdx.z == 3) {
        int n = blockIdx.y;
        int per = 2 * 66 + 2 * 64;               // 260 ring pixels
        for (int i = blockIdx.x * 256 + threadIdx.x; i < per; i += gridDim.x * 256) {
            int h, w;
            if (i < 66) { h = 0; w = i; }
            else if (i < 132) { h = 65; w = i - 66; }
            else { int q = i - 132; h = 1 + (q >> 1); w = (q & 1) ? 65 : 0; }
            idxb[((size_t)n * 66 + h) * 66 + w] = 512;
        }
        return;
    }
    unsigned short* buf; int Hp, Wp, PS;
    switch (blockIdx.z) {
        case 0: buf = a1; Hp = 258; Wp = 258; PS = 64; break;
        case 1: buf = a2; Hp = 130; Wp = 130; PS = 64; break;
        case 2: buf = a3; Hp = 66; Wp = 66; PS = 64; break;
        default: buf = d1; Hp = 66; Wp = 66; PS = 64; break;
    }
    int per = 2 * Wp + 2 * (Hp - 2);
    int chunks = PS >> 3;
    int total = per * chunks;
    int n = blockIdx.y;
    for (int i = blockIdx.x * 256 + threadIdx.x; i < total; i += gridDim.x * 256) {
        int pix = i / chunks, c = i - pix * chunks;
        int h, w;
        if (pix < Wp) { h = 0; w = pix; }
        else if (pix < 2 * Wp) { h = Hp - 1; w = pix - Wp; }
        else { int q = pix - 2 * Wp; h = 1 + (q >> 1); w = (q & 1) ? (Wp - 1) : 0; }
        uint4 zz = {0, 0, 0, 0};
        *(uint4*)(buf + (((size_t)n * Hp + h) * Wp + w) * PS + c * 8) = zz;
    }
}

// ---- weight/codebook prep helpers ------------------------------------------
__device__ inline void prep_conv_dev(const float* __restrict__ w,
    unsigned short* __restrict__ o, int Cout, int Cin, int T, int CIC, int idx)
{
    if (idx >= Cout * Cin * T) return;
    int tap = idx % T; int r = idx / T; int ci = r % Cin; int co = r / Cin;
    int chunk = ci / CIC, cil = ci % CIC;
    int k = chunk * (T * CIC) + tap * CIC + cil;
    int s = k >> 5, g = (k >> 3) & 3, j = k & 7;
    o[((size_t)(s * 4 + g) * Cout + co) * 8 + j] = (unsigned short)bf16rne(w[idx]);
}

__device__ inline void prep_wT_dev(const float* __restrict__ w,
    unsigned short* __restrict__ o, int idx)
{
    if (idx >= 65536) return;
    int ci = idx & 63; int r = idx >> 6;
    int jw = r & 1; r >>= 1;
    int jh = r & 1; r >>= 1;
    int co = r & 63; r >>= 6;
    int pw = r & 1; int ph = (r >> 1) & 1;
    int kh = (1 - ph) + 2 * (1 - jh);
    int kw = (1 - pw) + 2 * (1 - jw);
    int k = (jh * 2 + jw) * 64 + ci;
    int s = k >> 5, g = (k >> 3) & 3, j = k & 7;
    o[(size_t)(ph * 2 + pw) * 16384 + ((size_t)(s * 4 + g) * 64 + co) * 8 + j] =
        (unsigned short)bf16rne(w[((ci * 64 + co) * 4 + kh) * 4 + kw]);
}

// ---- all weight/cb/cn2 prep in one dispatch: grid (1152, 9) ----------------
__global__ __launch_bounds__(256) void k_prep_all(
    const float* __restrict__ enc_w2, const float* __restrict__ enc_w3,
    const float* __restrict__ enc_w4, const float* __restrict__ dec_w1,
    const float* __restrict__ tw1, const float* __restrict__ tw2,
    const float* __restrict__ cb,
    unsigned short* __restrict__ wA2, unsigned short* __restrict__ wA3,
    unsigned short* __restrict__ wB1, unsigned short* __restrict__ wB2,
    unsigned short* __restrict__ wC1, unsigned short* __restrict__ wC2,
    unsigned short* __restrict__ cbF, unsigned short* __restrict__ cbB,
    float* __restrict__ cn2)
{
    int idx = blockIdx.x * 256 + threadIdx.x;
    switch (blockIdx.y) {
    case 0: prep_conv_dev(enc_w2, wA2, 64, 64, 16, 64, idx); break;
    case 1: prep_conv_dev(enc_w3, wA3, 64, 64, 16, 64, idx); break;
    case 2: prep_conv_dev(enc_w4, wB1, 512, 64, 9, 64, idx); break;
    case 3: prep_conv_dev(dec_w1, wB2, 64, 512, 9, 64, idx); break;
    case 4: prep_wT_dev(tw1, wC1, idx); break;
    case 5: prep_wT_dev(tw2, wC2, idx); break;
    case 6: {
        if (idx < 262144) {
            int c = idx & 511, k = idx >> 9;
            int cblk = k >> 7, kl = k & 127, s = c >> 5, g = (c >> 3) & 3, j = c & 7;
            size_t off = ((((size_t)cblk * 16 + s) * 4 + g) * 128 + kl) * 8 + j;
            cbF[off] = f16bits(cb[idx]);
        }
    } break;
    case 7: {
        // bf16 codebook for dec1 gather-stage; row 512 = zeros (halo code)
        if (idx < 262144) cbB[idx] = (unsigned short)bf16rne(cb[idx]);
        else if (idx < 262656) cbB[idx] = 0;
    } break;
    default: {
        int code = blockIdx.x * 4 + (threadIdx.x >> 6);
        if (code < 512) {
            int l = threadIdx.x & 63;
            float s = 0.f;
#pragma unroll
            for (int i = 0; i < 8; ++i) {
                float v = cb[code * 512 + l + i * 64];
                s = fmaf(v, v, s);
            }
#pragma unroll
            for (int off = 32; off > 0; off >>= 1) s += __shfl_xor(s, off);
            if (l == 0) cn2[code] = 0.5f * s;
        }
    } break;
    }
}

// ---- enc conv1: Cin=1, 4x4 s2 p1, ReLU -> bf16 NHWC padded ----------------
__global__ __launch_bounds__(256) void k_conv1(const float* __restrict__ x,
    const float* __restrict__ w, const float* __restrict__ b, unsigned short* __restrict__ out)
{
    __shared__ __align__(16) unsigned short sh[128 * 132];
    int t = threadIdx.x;
    int oh = blockIdx.x;
    int n = blockIdx.y;
    int ow = t;
    const float* xn = x + (size_t)n * 262144;
    float xv[16];
#pragma unroll
    for (int kh = 0; kh < 4; ++kh) {
        int ih = 2 * oh - 1 + kh;
        bool rok = (unsigned)ih < 512u;
        int ihc = min(max(ih, 0), 511);
#pragma unroll
        for (int kw = 0; kw < 4; ++kw) {
            int iw = 2 * ow - 1 + kw;
            bool ok = rok && ((unsigned)iw < 512u);
            int iwc = min(max(iw, 0), 511);
            float v = xn[ihc * 512 + iwc];
            xv[kh * 4 + kw] = ok ? v : 0.f;
        }
    }
    unsigned uo[32];
#pragma unroll
    for (int co2 = 0; co2 < 32; ++co2) {
        float a0 = b[2 * co2], a1 = b[2 * co2 + 1];
#pragma unroll
        for (int q = 0; q < 16; ++q) {
            a0 = fmaf(xv[q], w[(2 * co2) * 16 + q], a0);
            a1 = fmaf(xv[q], w[(2 * co2 + 1) * 16 + q], a1);
        }
        uo[co2] = pack2(fmaxf(a0, 0.f), fmaxf(a1, 0.f));
    }
    unsigned short* rowbase = out + (((size_t)n * 258 + oh + 1) * 258 + 1) * 64;
#pragma unroll
    for (int pass = 0; pass < 2; ++pass) {
        if (pass) __syncthreads();               // protect pass-0 reads
        if ((t >> 7) == pass) {
            int p = t & 127;
            unsigned short* rowp = sh + (size_t)p * 132;
#pragma unroll
            for (int i = 0; i < 8; ++i) {
                uint4 st = {uo[4 * i], uo[4 * i + 1], uo[4 * i + 2], uo[4 * i + 3]};
                *(uint4*)(rowp + i * 8) = st;
            }
        }
        __syncthreads();
        unsigned short* gbase = rowbase + (size_t)pass * 8192;
#pragma unroll
        for (int i = 0; i < 4; ++i) {
            int s = i * 256 + t;                 // lane-consecutive slots
            int p = s >> 3, c = s & 7;
            uint4 v = *(const uint4*)(sh + (size_t)p * 132 + c * 8);
            *(uint4*)(gbase + (size_t)s * 8) = v;
        }
    }
}

__device__ inline bool better_sc(float av, int ai, float bv, int bi) {
    return av > bv || (av == bv && ai < bi);
}

// ---- VQ approx GEMM pass-1: fp16 single-term, top-2 per 128-code block -----
__global__ __launch_bounds__(256) void k_vqgemm(
    const unsigned short* __restrict__ zH, const unsigned short* __restrict__ cbF,
    const float* __restrict__ cn2, int* __restrict__ candI)
{
    __shared__ __align__(16) unsigned short shA[20480];  // 2 bufs x (2 steps x 640 slots x 8)
    int t = threadIdx.x, lane = t & 63, wv = t >> 6;
    int wc = wv & 1, wr = wv >> 1;
    int m = lane & 15, g = lane >> 4;
    int L = blockIdx.x;
    int xcd = L & 7, kk = L >> 3;
    int cblk = kk & 3;
    int row0 = ((kk >> 2) + xcd * 32) * 128;

    f32x4_t acc[4][4];
#pragma unroll
    for (int a = 0; a < 4; ++a)
#pragma unroll
        for (int b = 0; b < 4; ++b) acc[a][b] = (f32x4_t){0.f, 0.f, 0.f, 0.f};

    const uint4* bF = (const uint4*)cbF + (size_t)cblk * 8192;

    auto stage = [&](int c, int bi) {
        unsigned short* dst = shA + (size_t)bi * 10240;
        for (int q = t; q < 1280; q += 256) {
            int ss = q / 640, rest = q - ss * 640;
            int r = rest / 5, seg = rest - r * 5;
            int s = c * 2 + ss;
            gl_lds16(zH + ((size_t)s * 32768 + row0 + r) * 32 + (seg & 3) * 8,
                     dst + (size_t)q * 8);
        }
    };

    stage(0, 0);
    __syncthreads();
    for (int c = 0; c < 8; ++c) {
        if (c + 1 < 8) stage(c + 1, (c + 1) & 1);
        const unsigned short* buf = shA + (size_t)(c & 1) * 10240;
#pragma unroll
        for (int ss = 0; ss < 2; ++ss) {
            int s = c * 2 + ss;
            Frag16 B[4];
#pragma unroll
            for (int ni = 0; ni < 4; ++ni)
                B[ni].u = bF[(s * 4 + g) * 128 + wc * 64 + ni * 16 + m];
#pragma unroll
            for (int mi = 0; mi < 4; ++mi) {
                Frag16 A;
                A.u = *(const uint4*)(buf + (size_t)(ss * 5120 + (wr * 64 + mi * 16 + m) * 40 + g * 8));
#pragma unroll
                for (int ni = 0; ni < 4; ++ni)
                    acc[mi][ni] = mfma16h(A.h, B[ni].h, acc[mi][ni]);
            }
        }
        if (c + 1 < 8) __syncthreads();
    }
    // argmax scratch aliases into buffer0 region (barrier-separated).
    float* tV = (float*)shA;                 // [wc2][row128][cand2]
    int*   tI = (int*)(shA + 2048);          // byte off 4096, same shape
    float c2v[4];
#pragma unroll
    for (int ni = 0; ni < 4; ++ni) c2v[ni] = cn2[cblk * 128 + wc * 64 + ni * 16 + m];
    int ixb = cblk * 128 + wc * 64 + m;
#pragma unroll
    for (int mi = 0; mi < 4; ++mi) {
#pragma unroll
        for (int r = 0; r < 4; ++r) {
            float a0 = acc[mi][0][r] - c2v[0];
            float a1 = acc[mi][1][r] - c2v[1];
            float a2 = acc[mi][2][r] - c2v[2];
            float a3 = acc[mi][3][r] - c2v[3];
            bool cA = a1 > a0;
            float p1 = cA ? a1 : a0; int pi1 = cA ? ixb + 16 : ixb;
            float p2 = cA ? a0 : a1; int pi2 = cA ? ixb : ixb + 16;
            bool cB = a3 > a2;
            float q1 = cB ? a3 : a2; int qi1 = cB ? ixb + 48 : ixb + 32;
            float q2 = cB ? a2 : a3; int qi2 = cB ? ixb + 32 : ixb + 48;
            bool cC = q1 > p1;
            float v1 = cC ? q1 : p1; int i1 = cC ? qi1 : pi1;
            float sa = cC ? p1 : q1; int sai = cC ? pi1 : qi1;
            float sb = cC ? q2 : p2; int sbi = cC ? qi2 : pi2;
            bool cD = sb > sa;
            float v2 = cD ? sb : sa; int i2 = cD ? sbi : sai;
#pragma unroll
            for (int off = 1; off < 16; off <<= 1) {
                float o1 = __shfl_xor(v1, off); int oi1 = __shfl_xor(i1, off);
                float o2 = __shfl_xor(v2, off); int oi2 = __shfl_xor(i2, off);
                bool c = o1 > v1;
                float w2 = c ? v1 : v2; int w2i = c ? i1 : i2;
                float u2 = c ? o2 : o1; int u2i = c ? oi2 : oi1;
                v1 = c ? o1 : v1; i1 = c ? oi1 : i1;
                bool cc = u2 > w2;
                v2 = cc ? u2 : w2; i2 = cc ? u2i : w2i;
            }
            if (m == 0) {
                int row = wr * 64 + mi * 16 + g * 4 + r;
                tV[(wc * 128 + row) * 2 + 0] = v1; tI[(wc * 128 + row) * 2 + 0] = i1;
                tV[(wc * 128 + row) * 2 + 1] = v2; tI[(wc * 128 + row) * 2 + 1] = i2;
            }
        }
    }
    __syncthreads();
    if (t < 128) {
        float v1 = tV[t * 2], v2 = tV[t * 2 + 1];
        int i1 = tI[t * 2], i2 = tI[t * 2 + 1];
        float o1 = tV[(128 + t) * 2], o2 = tV[(128 + t) * 2 + 1];
        int oi1 = tI[(128 + t) * 2], oi2 = tI[(128 + t) * 2 + 1];
        bool c = o1 > v1;
        float w2 = c ? v1 : v2; int w2i = c ? i1 : i2;
        float u2 = c ? o2 : o1; int u2i = c ? oi2 : oi1;
        v1 = c ? o1 : v1; i1 = c ? oi1 : i1;
        bool cc = u2 > w2;
        v2 = cc ? u2 : w2; i2 = cc ? u2i : w2i;
        candI[((size_t)cblk * 2 + 0) * 32768 + row0 + t] = i1;
        candI[((size_t)cblk * 2 + 1) * 32768 + row0 + t] = i2;
    }
}

// ---- VQ pass-2: wave-per-row exact fp32 rescore -> idx map + mind ----------
__global__ __launch_bounds__(256) void k_vqfinal(
    const unsigned short* __restrict__ zH, const unsigned short* __restrict__ zL,
    const float* __restrict__ cb, const int* __restrict__ candI,
    int* __restrict__ idxb, float* __restrict__ mind)
{
    int t = threadIdx.x, lane = t & 63, wv = t >> 6;
    int row = blockIdx.x * 4 + wv;
    size_t zoff = ((size_t)(lane >> 2) * 32768 + row) * 32 + (lane & 3) * 8;
    uint4 hu = *(const uint4*)(zH + zoff);
    uint4 lu = *(const uint4*)(zL + zoff);
    float z0 = f16lo(hu.x) + f16lo(lu.x);
    float z1 = f16hi(hu.x) + f16hi(lu.x);
    float z2 = f16lo(hu.y) + f16lo(lu.y);
    float z3 = f16hi(hu.y) + f16hi(lu.y);
    float z4 = f16lo(hu.z) + f16lo(lu.z);
    float z5 = f16hi(hu.z) + f16hi(lu.z);
    float z6 = f16lo(hu.w) + f16lo(lu.w);
    float z7 = f16hi(hu.w) + f16hi(lu.w);
    int mycand = (lane < 8) ? candI[(size_t)lane * 32768 + row] : 0;
    int cands[8];
    float d[8];
#pragma unroll
    for (int s = 0; s < 8; ++s) cands[s] = __shfl(mycand, s);
#pragma unroll
    for (int s = 0; s < 8; ++s) {
        const float* cr = cb + (size_t)cands[s] * 512 + lane * 8;
        float4 c0 = *(const float4*)cr;
        float4 c1 = *(const float4*)(cr + 4);
        float e, dd = 0.f;
        e = z0 - c0.x; dd = fmaf(e, e, dd);
        e = z1 - c0.y; dd = fmaf(e, e, dd);
        e = z2 - c0.z; dd = fmaf(e, e, dd);
        e = z3 - c0.w; dd = fmaf(e, e, dd);
        e = z4 - c1.x; dd = fmaf(e, e, dd);
        e = z5 - c1.y; dd = fmaf(e, e, dd);
        e = z6 - c1.z; dd = fmaf(e, e, dd);
        e = z7 - c1.w; dd = fmaf(e, e, dd);
        d[s] = dd;
    }
#pragma unroll
    for (int off = 1; off < 64; off <<= 1) {
#pragma unroll
        for (int s = 0; s < 8; ++s) d[s] += __shfl_xor(d[s], off);
    }
    float bd = d[0]; int bi_ = cands[0];
#pragma unroll
    for (int s = 1; s < 8; ++s) {
        if (d[s] < bd || (d[s] == bd && cands[s] < bi_)) { bd = d[s]; bi_ = cands[s]; }
    }
    if (lane == 0) {
        int n = row >> 12, hw = row & 4095, h = hw >> 6, w = hw & 63;
        idxb[((size_t)(n * 66 + h + 1)) * 66 + (w + 1)] = bi_;
        mind[row] = bd;
    }
}

// ---- final conv-transpose 64 -> 1, sigmoid (LDS-staged, fp16 dot2) ---------
__global__ __launch_bounds__(256, 4) void k_convt_final2(const unsigned short* __restrict__ xp,
    const float* __restrict__ w, const float* __restrict__ b, float* __restrict__ out)
{
    __shared__ __align__(16) unsigned short shx[3 * 1040 * 8];
    __shared__ __align__(16) unsigned wp[16][32];
    int t = threadIdx.x, lane = t & 63, wv = t >> 6;
    int bx = blockIdx.x, q = blockIdx.y, n = blockIdx.z;
    int colbase = bx * 128;
#pragma unroll
    for (int i = 0; i < 2; ++i) {
        int qq = t + i * 256;
        int tap = qq >> 5, c2 = qq & 31;
        wp[tap][c2] = pack2h(w[(2 * c2) * 16 + tap], w[(2 * c2 + 1) * 16 + tap]);
    }
    const unsigned short* an = xp + (size_t)n * 258 * 258 * 64;
    for (int u_ = wv; u_ < 51; u_ += 4) {
        int r = u_ / 17, seg = u_ % 17;
        int slot = seg * 64 + lane;
        if (slot < 1040) {
            int p = slot >> 3, uu = slot & 7;
            int su = (uu - p) & 7;
            int row = min(2 * q + r, 257);
            const unsigned short* gsrc = an + ((size_t)row * 258 + colbase + p) * 64 + su * 8;
            gl_lds16(gsrc, shx + ((size_t)(r * 1040 + slot)) * 8);
        }
    }
    __syncthreads();
    int ow = bx * 256 + t;
    int kwA = (ow + 1) & 1;
    int cA = ((ow + 1) >> 1) + 1 - colbase;
    int cB = cA - 1;
    float b0 = b[0];
    float acc0 = b0, acc1 = b0, acc2 = b0, acc3 = b0;
#pragma unroll 2
    for (int c8 = 0; c8 < 8; ++c8) {
        uint4 xr[3][2];
#pragma unroll
        for (int r = 0; r < 3; ++r) {
            xr[r][0] = *(const uint4*)(shx + (size_t)(r * 1040 + cB * 8 + ((c8 + cB) & 7)) * 8);
            xr[r][1] = *(const uint4*)(shx + (size_t)(r * 1040 + cA * 8 + ((c8 + cA) & 7)) * 8);
        }
        uint4 wA[4], wB[4];
#pragma unroll
        for (int kh = 0; kh < 4; ++kh) {
            wA[kh] = *(const uint4*)&wp[kh * 4 + kwA][c8 * 4];
            wB[kh] = *(const uint4*)&wp[kh * 4 + kwA + 2][c8 * 4];
        }
        acc0 = dot8(xr[1][1], wA[0], acc0); acc0 = dot8(xr[1][0], wB[0], acc0);
        acc0 = dot8(xr[0][1], wA[2], acc0); acc0 = dot8(xr[0][0], wB[2], acc0);
        acc1 = dot8(xr[1][1], wA[1], acc1); acc1 = dot8(xr[1][0], wB[1], acc1);
        acc1 = dot8(xr[0][1], wA[3], acc1); acc1 = dot8(xr[0][0], wB[3], acc1);
        acc2 = dot8(xr[2][1], wA[0], acc2); acc2 = dot8(xr[2][0], wB[0], acc2);
        acc2 = dot8(xr[1][1], wA[2], acc2); acc2 = dot8(xr[1][0], wB[2], acc2);
        acc3 = dot8(xr[2][1], wA[1], acc3); acc3 = dot8(xr[2][0], wB[1], acc3);
        acc3 = dot8(xr[1][1], wA[3], acc3); acc3 = dot8(xr[1][0], wB[3], acc3);
    }
    float accs[4] = {acc0, acc1, acc2, acc3};
    float* on = out + (size_t)n * 262144;
#pragma unroll
    for (int ro = 0; ro < 4; ++ro) {
        int oh = 4 * q - 1 + ro;
        if ((unsigned)oh < 512u)
            on[(size_t)oh * 512 + ow] = 1.0f / (1.0f + __expf(-accs[ro]));
    }
}

// ---- finalize loss: single-block reduction over mind[32768] ----------------
__global__ __launch_bounds__(256) void k_loss_final(const float* __restrict__ mind,
    float* __restrict__ out)
{
    __shared__ float redd[4];
    int t = threadIdx.x;
    float s = 0.f;
#pragma unroll 4
    for (int i = 0; i < 32; ++i) {
        float4 v = *(const float4*)(mind + i * 1024 + t * 4);
        s += v.x + v.y + v.z + v.w;
    }
#pragma unroll
    for (int off = 1; off < 64; off <<= 1) s += __shfl_xor(s, off);
    if ((t & 63) == 0) redd[t >> 6] = s;
    __syncthreads();
    if (t == 0)
        out[0] = 1.25f * (redd[0] + redd[1] + redd[2] + redd[3]) * (1.0f / 16777216.0f);
}

// ---------------------------------------------------------------------------
extern "C" void kernel_launch(void* const* d_in, const int* in_sizes, int n_in,
                              void* d_out, int out_size, void* d_ws, size_t ws_size,
                              hipStream_t stream)
{
    const float* x      = (const float*)d_in[0];
    const float* enc_w1 = (const float*)d_in[1];
    const float* enc_b1 = (const float*)d_in[2];
    const float* enc_w2 = (const float*)d_in[3];
    const float* enc_b2 = (const float*)d_in[4];
    const float* enc_w3 = (const float*)d_in[5];
    const float* enc_b3 = (const float*)d_in[6];
    const float* enc_w4 = (const float*)d_in[7];
    const float* enc_b4 = (const float*)d_in[8];
    const float* cb     = (const float*)d_in[9];
    const float* dec_w1 = (const float*)d_in[10];
    const float* dec_b1 = (const float*)d_in[11];
    const float* tw1    = (const float*)d_in[12];
    const float* tb1    = (const float*)d_in[13];
    const float* tw2    = (const float*)d_in[14];
    const float* tb2    = (const float*)d_in[15];
    const float* tw3    = (const float*)d_in[16];
    const float* tb3    = (const float*)d_in[17];
    float* out = (float*)d_out;

    unsigned short* a1 = (unsigned short*)d_ws;        // 8*258*258*64
    unsigned short* a2 = a1 + 34076672;                // 8*130*130*64
    unsigned short* a3 = a2 + 8652800;                 // 8*66*66*64
    unsigned short* zH = a3 + 2230272;                 // 16*32768*32 (fp16)
    unsigned short* zL = zH + 16777216;                // 16*32768*32 (fp16)
    unsigned short* zqr = zL + 16777216;               // ex-zq region (reused)
    unsigned short* d1 = zqr + 17842176;               // 8*66*66*64
    unsigned short* wA2 = d1 + 2230272;                // 65536
    unsigned short* wA3 = wA2 + 65536;
    unsigned short* wB1 = wA3 + 65536;                 // 294912
    unsigned short* wB2 = wB1 + 294912;                // 294912
    unsigned short* wC1 = wB2 + 294912;                // 65536
    unsigned short* wC2 = wC1 + 65536;                 // 65536
    unsigned short* cbF = wC2 + 65536;                 // 262144 (fp16 frag)
    float* cn2 = (float*)(cbF + 262144);               // 512
    int*   candI = (int*)(cn2 + 512);                  // 8*32768
    float* mind = (float*)(candI + 262144);            // 32768
    int*   idxb = (int*)zqr;                           // 8*66*66 ints (139KB)
    unsigned short* cbB = zqr + 2 * 34848;             // 513*512 bf16 (525KB)
    float* pf = (float*)zH;                            // dec1 partials (zH dead after vqfinal)

    // consolidated halos + preps
    k_halo_all<<<dim3(65, 8, 5), 256, 0, stream>>>(a1, a2, a3, idxb, d1);
    k_prep_all<<<dim3(1152, 9), 256, 0, stream>>>(
        enc_w2, enc_w3, enc_w4, dec_w1, tw1, tw2, cb,
        wA2, wA3, wB1, wB2, wC1, wC2, cbF, cbB, cn2);

    // pipeline
    k_conv1<<<dim3(256, 8), 256, 0, stream>>>(x, enc_w1, enc_b1, a1);
    k_enc2w<<<dim3(128, 8), 256, 0, stream>>>(a1, wA2, enc_b2, a2);
    conv_mfma<4, 4, 2, 64, 32, 1, 0, 0><<<dim3(2, 64, 8), 256, 0, stream>>>(
        a2, wA3, enc_b3, a3, 130, 130, 64, 1, 64, 1, 66, 66, 1, nullptr);
    k_enc4<<<1024, 256, 0, stream>>>(a3, wB1, enc_b4, zH, zL);
    k_vqgemm<<<1024, 256, 0, stream>>>(zH, cbF, cn2, candI);
    k_vqfinal<<<8192, 256, 0, stream>>>(zH, zL, cb, candI, idxb, mind);
    // dec1 K-split x2, gather-stage from L2-resident cbB via idx map
    conv_mfma<3, 3, 1, 64, 64, 2, 5, 0><<<dim3(2, 64, 8), 256, 0, stream>>>(
        cbB, wB2, dec_b1, pf, 66, 66, 512, 4, 64, 1, 66, 66, 0, idxb);
    k_dec1red<<<1024, 256, 0, stream>>>(pf, dec_b1, d1);
    k_convtf<0><<<dim3(1, 128, 8), 256, 0, stream>>>(d1, wC1, tb1, a2, 66, 66, 130, 130);
    k_convtf<3><<<dim3(2, 256, 8), 256, 0, stream>>>(a2, wC2, tb2, a1, 130, 130, 258, 258);
    k_convt_final2<<<dim3(2, 129, 8), 256, 0, stream>>>(a1, tw3, tb3, out);
    k_loss_final<<<1, 256, 0, stream>>>(mind, out + 2097152);
}

// Round 18
// 379.100 us; speedup vs baseline: 1.0209x; 1.0010x over previous
//
#include <hip/hip_runtime.h>
#include <math.h>

// ---------------------------------------------------------------------------
// VQ-VAE forward, bf16-MFMA. Round 31: pf (dec1 K-split partials) fp32 -> fp16
// (33.5MB -> 16.8MB write + same read; partial magnitudes ~5e-3, fp16 abs
// error ~5e-6 — negligible vs 0.0042 current absmax). conv_mfma OUTM>=4 packs
// pack2h uint2; k_dec1red reads uint4 halves per slab. Everything else = R30
// (379.5us best: zq eliminated via idx map + L2-resident cbB gather-stage).
// ---------------------------------------------------------------------------

typedef __bf16 bf16x8_t __attribute__((ext_vector_type(8)));
typedef _Float16 f16x8_t __attribute__((ext_vector_type(8)));
typedef float f32x4_t __attribute__((ext_vector_type(4)));
typedef _Float16 h2_t __attribute__((ext_vector_type(2)));

union FragU { uint4 u; bf16x8_t b; };
union Frag16 { uint4 u; f16x8_t h; };

__device__ inline f32x4_t mfma16(bf16x8_t a, bf16x8_t b, f32x4_t c) {
    return __builtin_amdgcn_mfma_f32_16x16x32_bf16(a, b, c, 0, 0, 0);
}
__device__ inline f32x4_t mfma16h(f16x8_t a, f16x8_t b, f32x4_t c) {
    return __builtin_amdgcn_mfma_f32_16x16x32_f16(a, b, c, 0, 0, 0);
}

__device__ inline void gl_lds16(const void* g, void* l) {
    __builtin_amdgcn_global_load_lds((const __attribute__((address_space(1))) void*)g,
                                     (__attribute__((address_space(3))) void*)l, 16, 0, 0);
}

__device__ inline unsigned bf16rne(float f) {
    unsigned u = __float_as_uint(f);
    u += 0x7FFFu + ((u >> 16) & 1u);
    return u >> 16;
}
__device__ inline unsigned pack2(float lo, float hi) {
    return bf16rne(lo) | (bf16rne(hi) << 16);
}
__device__ inline unsigned pack2h(float lo, float hi) {
    union { h2_t h; unsigned u; } r;
    r.h[0] = (_Float16)lo; r.h[1] = (_Float16)hi;
    return r.u;
}
__device__ inline unsigned short f16bits(float v) {
    union { _Float16 h; unsigned short s; } x; x.h = (_Float16)v; return x.s;
}
__device__ inline float f16lo(unsigned u) {
    union { unsigned u; h2_t h; } x; x.u = u; return (float)x.h[0];
}
__device__ inline float f16hi(unsigned u) {
    union { unsigned u; h2_t h; } x; x.u = u; return (float)x.h[1];
}
__device__ inline float bl(unsigned u) { return __uint_as_float(u << 16); }
__device__ inline float bh(unsigned u) { return __uint_as_float(u & 0xffff0000u); }

#if defined(__has_builtin)
#if __has_builtin(__builtin_amdgcn_fdot2)
#define HAS_FDOT2 1
#endif
#endif

__device__ inline float dot2h(unsigned x, unsigned w, float a) {
#ifdef HAS_FDOT2
    union { unsigned u; h2_t h; } ax, bw;
    ax.u = x; bw.u = w;
    return __builtin_amdgcn_fdot2(ax.h, bw.h, a, false);
#else
    union { unsigned u; _Float16 h[2]; } ax, bw;
    ax.u = x; bw.u = w;
    a = fmaf((float)ax.h[0], (float)bw.h[0], a);
    return fmaf((float)ax.h[1], (float)bw.h[1], a);
#endif
}
__device__ inline float dot8(uint4 x, uint4 w, float a) {
    a = dot2h(x.x, w.x, a); a = dot2h(x.y, w.y, a);
    a = dot2h(x.z, w.z, a); a = dot2h(x.w, w.w, a);
    return a;
}

// ---- generic implicit-GEMM conv (enc3, dec1) -------------------------------
// DBUF=1: double-buffered LDS; stage(ch+1) issued before compute(ch).
// OUTM==4: K-split partial mode — blockIdx.x selects the chunk-half, output
// is fp16 acc (no bias/relu) to [khalf][nb][4096pix][64ch] halves.
// OUTM==5: same + GATHER stage: in = cbB[513][512] bf16 codebook,
// idxb = halo'd [66][66] per-n code map (512 -> zero row).
template<int NR, int KW_, int SW, int CIC, int SPT, int NT, int OUTM, int DBUF>
__global__ __launch_bounds__(256) void conv_mfma(
    const unsigned short* __restrict__ in, const unsigned short* __restrict__ wp,
    const float* __restrict__ bias, void* __restrict__ outp,
    int Hp, int Wp, int PS, int nchunks, int Cout, int ncog,
    int Hpo, int Wpo, int relu, const int* __restrict__ idxb)
{
    constexpr int W_ST = SW * (SPT - 1) + KW_;
    constexpr int SLOTS_PP = CIC / 8;
    constexpr int ROW_SLOTS = W_ST * SLOTS_PP;
    constexpr int SEGS = (ROW_SLOTS + 63) / 64;
    constexpr int KT = NR * KW_;
    constexpr int CSTEPS = CIC / 32;
    constexpr int BUFSZ = NR * W_ST * CIC;
    __shared__ __align__(16) unsigned short sh[(DBUF ? 2 : 1) * BUFSZ];

    int t = threadIdx.x, lane = t & 63, wv = t >> 6;
    int bx = blockIdx.x;
    int owt, khalf;
    if constexpr (OUTM >= 4) { khalf = bx; owt = 0; }
    else { khalf = 0; owt = bx; }
    int ch0 = khalf * nchunks;
    int ohg = blockIdx.y;
    int bz = blockIdx.z; int nb = bz / ncog; int cog = bz % ncog;
    int ow0 = owt * SPT;
    int row0 = SW * ohg;
    int col0 = SW * ow0;
    int coh = wv & 1;
    int sph = wv >> 1;
    int m = lane & 15, g = lane >> 4;

    f32x4_t acc[2][NT];
#pragma unroll
    for (int a = 0; a < 2; ++a)
#pragma unroll
        for (int u2 = 0; u2 < NT; ++u2) acc[a][u2] = (f32x4_t){0.f, 0.f, 0.f, 0.f};

    auto stage = [&](int ch, unsigned short* buf) {
        for (int u_ = wv; u_ < NR * SEGS; u_ += 4) {
            int r = u_ / SEGS, seg = u_ - r * SEGS;
            int slot = seg * 64 + lane;
            int p = slot / SLOTS_PP;
            int uu = slot & (SLOTS_PP - 1);
            if (p < W_ST) {
                int su = (uu - (p & 7)) & (SLOTS_PP - 1);
                const unsigned short* gsrc;
                if constexpr (OUTM == 5) {
                    int code = idxb[((size_t)nb * Hp + (row0 + r)) * Wp + (col0 + p)];
                    gsrc = in + (size_t)code * 512 + (ch0 + ch) * CIC + su * 8;
                } else {
                    gsrc = in +
                        (((size_t)nb * Hp + (row0 + r)) * Wp + (col0 + p)) * PS + (ch0 + ch) * CIC + su * 8;
                }
                unsigned short* ldst = buf + ((size_t)(r * ROW_SLOTS + seg * 64 + lane)) * 8;
                gl_lds16(gsrc, ldst);
            }
        }
    };

    auto compute = [&](int ch, const unsigned short* buf) {
        int sbase = (ch0 + ch) * (KT * CSTEPS);
#pragma unroll
        for (int tap = 0; tap < KT; ++tap) {
            const int r_l = tap / KW_, kwp = tap % KW_;
#pragma unroll
            for (int cs = 0; cs < CSTEPS; ++cs) {
                int s = sbase + tap * CSTEPS + cs;
                const uint4* wr = (const uint4*)wp + (size_t)(s * 4 + g) * Cout + cog * 64 + coh * 32 + m;
                FragU a0, a1;
                a0.u = wr[0];
                a1.u = wr[16];
#pragma unroll
                for (int u2 = 0; u2 < NT; ++u2) {
                    int sp_l = sph * (SPT / 2) + u2 * 16 + m;
                    int p = SW * sp_l + kwp;
                    int off = (cs * 32 + g * 8 + ((p & 7) << 3)) & (CIC - 1);
                    FragU bb;
                    bb.u = *(const uint4*)(buf + (size_t)(r_l * W_ST + p) * CIC + off);
                    acc[0][u2] = mfma16(a0.b, bb.b, acc[0][u2]);
                    acc[1][u2] = mfma16(a1.b, bb.b, acc[1][u2]);
                }
            }
        }
    };

    stage(0, sh);
    __syncthreads();
    for (int ch = 0; ch < nchunks; ++ch) {
        if constexpr (DBUF != 0) {
            if (ch + 1 < nchunks) stage(ch + 1, sh + (size_t)((ch + 1) & 1) * BUFSZ);
        }
        compute(ch, DBUF ? (sh + (size_t)(ch & 1) * BUFSZ) : sh);
        if (ch + 1 < nchunks) {
            if constexpr (DBUF == 0) {
                __syncthreads();
                stage(ch + 1, sh);
            }
            __syncthreads();
        }
    }
    if constexpr (OUTM >= 4) {
        unsigned short* ob = (unsigned short*)outp;
#pragma unroll
        for (int a = 0; a < 2; ++a) {
#pragma unroll
            for (int u2 = 0; u2 < NT; ++u2) {
                int ow = ow0 + sph * (SPT / 2) + u2 * 16 + m;
                uint2 st = {pack2h(acc[a][u2][0], acc[a][u2][1]),
                            pack2h(acc[a][u2][2], acc[a][u2][3])};
                *(uint2*)(ob + ((((size_t)khalf * 8 + nb) * 4096 + ohg * 64 + ow) * 64
                          + (coh * 32 + a * 16 + g * 4))) = st;
            }
        }
    } else {
#pragma unroll
        for (int a = 0; a < 2; ++a) {
            int co = cog * 64 + coh * 32 + a * 16 + g * 4;
            float4 bv = *(const float4*)(bias + co);
#pragma unroll
            for (int u2 = 0; u2 < NT; ++u2) {
                int ow = ow0 + sph * (SPT / 2) + u2 * 16 + m;
                float v0 = acc[a][u2][0] + bv.x;
                float v1 = acc[a][u2][1] + bv.y;
                float v2 = acc[a][u2][2] + bv.z;
                float v3 = acc[a][u2][3] + bv.w;
                if (relu) {
                    v0 = fmaxf(v0, 0.f); v1 = fmaxf(v1, 0.f);
                    v2 = fmaxf(v2, 0.f); v3 = fmaxf(v3, 0.f);
                }
                unsigned short* ob = (unsigned short*)outp;
                uint2 st;
                if constexpr (OUTM == 3) st = (uint2){pack2h(v0, v1), pack2h(v2, v3)};
                else                     st = (uint2){pack2(v0, v1), pack2(v2, v3)};
                *(uint2*)(ob + (((size_t)nb * Hpo + ohg + 1) * Wpo + (ow + 1)) * 64
                          + (coh * 32 + a * 16 + g * 4)) = st;
            }
        }
    }
}

// ---- dec1 K-split reduce: sum fp16 halves + bias + ReLU -> bf16 d1 halo ----
__global__ __launch_bounds__(256) void k_dec1red(const unsigned short* __restrict__ pf,
    const float* __restrict__ bias, unsigned short* __restrict__ d1)
{
    int idx = blockIdx.x * 256 + threadIdx.x;     // 262144 total
    int c8 = idx & 7;
    int rest = idx >> 3;                          // n*4096 + pix
    int pix = rest & 4095, n = rest >> 12;
    const unsigned short* p0 = pf + (size_t)rest * 64 + c8 * 8;
    const unsigned short* p1 = p0 + (size_t)8 * 4096 * 64;   // khalf slab (shorts)
    uint4 a = *(const uint4*)p0;
    uint4 b = *(const uint4*)p1;
    float4 s0 = *(const float4*)(bias + c8 * 8);
    float4 s1 = *(const float4*)(bias + c8 * 8 + 4);
    float v0 = fmaxf(f16lo(a.x) + f16lo(b.x) + s0.x, 0.f);
    float v1 = fmaxf(f16hi(a.x) + f16hi(b.x) + s0.y, 0.f);
    float v2 = fmaxf(f16lo(a.y) + f16lo(b.y) + s0.z, 0.f);
    float v3 = fmaxf(f16hi(a.y) + f16hi(b.y) + s0.w, 0.f);
    float v4 = fmaxf(f16lo(a.z) + f16lo(b.z) + s1.x, 0.f);
    float v5 = fmaxf(f16hi(a.z) + f16hi(b.z) + s1.y, 0.f);
    float v6 = fmaxf(f16lo(a.w) + f16lo(b.w) + s1.z, 0.f);
    float v7 = fmaxf(f16hi(a.w) + f16hi(b.w) + s1.w, 0.f);
    uint4 st = {pack2(v0, v1), pack2(v2, v3), pack2(v4, v5), pack2(v6, v7)};
    int h = pix >> 6, w = pix & 63;
    *(uint4*)(d1 + ((size_t)(n * 66 + h + 1) * 66 + (w + 1)) * 64 + c8 * 8) = st;
}

// ---- enc2: 4x4 s2 conv 64->64, full-row blocks (64co x 128sp) --------------
__global__ __launch_bounds__(256) void k_enc2w(
    const unsigned short* __restrict__ in, const unsigned short* __restrict__ wp,
    const float* __restrict__ bias, unsigned short* __restrict__ out)
{
    __shared__ __align__(16) unsigned short sh[16512];   // 258 px x 64 ch
    int t = threadIdx.x, lane = t & 63, wv = t >> 6;
    int m = lane & 15, g = lane >> 4;
    int ohg = blockIdx.x, n = blockIdx.y;

    f32x4_t acc[4][2];
#pragma unroll
    for (int a = 0; a < 4; ++a)
#pragma unroll
        for (int u2 = 0; u2 < 2; ++u2) acc[a][u2] = (f32x4_t){0.f, 0.f, 0.f, 0.f};

    const uint4* wp4 = (const uint4*)wp;
#pragma unroll
    for (int kh = 0; kh < 4; ++kh) {
        if (kh) __syncthreads();
        const unsigned short* rowp = in + ((size_t)(n * 258 + 2 * ohg + kh) * 258) * 64;
        for (int q = t; q < 2064; q += 256) {
            int p = q >> 3, uu = q & 7;
            int su = (uu - ((p >> 1) & 7)) & 7;
            gl_lds16(rowp + (size_t)p * 64 + su * 8, sh + (size_t)q * 8);
        }
        __syncthreads();
#pragma unroll
        for (int kwp = 0; kwp < 4; ++kwp) {
#pragma unroll
            for (int cs = 0; cs < 2; ++cs) {
                int s = (kh * 4 + kwp) * 2 + cs;
                const uint4* wr = wp4 + (size_t)(s * 4 + g) * 64 + m;
                FragU A[4];
#pragma unroll
                for (int a = 0; a < 4; ++a) A[a].u = wr[a * 16];
#pragma unroll
                for (int u2 = 0; u2 < 2; ++u2) {
                    int sp_l = wv * 32 + u2 * 16 + m;
                    int p = 2 * sp_l + kwp;
                    int rot = (sp_l + (kwp >> 1)) & 7;
                    int off = (cs * 32 + g * 8 + rot * 8) & 63;
                    FragU B;
                    B.u = *(const uint4*)(sh + (size_t)p * 64 + off);
#pragma unroll
                    for (int a = 0; a < 4; ++a)
                        acc[a][u2] = mfma16(A[a].b, B.b, acc[a][u2]);
                }
            }
        }
    }
#pragma unroll
    for (int a = 0; a < 4; ++a) {
        float4 bv = *(const float4*)(bias + a * 16 + g * 4);
#pragma unroll
        for (int u2 = 0; u2 < 2; ++u2) {
            int ow = wv * 32 + u2 * 16 + m;
            float v0 = fmaxf(acc[a][u2][0] + bv.x, 0.f);
            float v1 = fmaxf(acc[a][u2][1] + bv.y, 0.f);
            float v2 = fmaxf(acc[a][u2][2] + bv.z, 0.f);
            float v3 = fmaxf(acc[a][u2][3] + bv.w, 0.f);
            uint2 st = {pack2(v0, v1), pack2(v2, v3)};
            *(uint2*)(out + ((size_t)(n * 130 + ohg + 1) * 130 + ow + 1) * 64
                      + a * 16 + g * 4) = st;
        }
    }
}

// ---- fused conv-transpose 4x4 s2: one output-row (ph) per block ------------
// ph-split for TLP — block stages 2 input rows (17KB LDS), waves split
// (pw, u2-half), acc[4][2]. Epilogue: contiguous-row store ([128][68] alias).
template<int OUTM>
__global__ __launch_bounds__(256) void k_convtf(
    const unsigned short* __restrict__ in, const unsigned short* __restrict__ wp,
    const float* __restrict__ bias, unsigned short* __restrict__ out,
    int Hpi, int Wpi, int Hpo, int Wpo)
{
    __shared__ __align__(16) unsigned short sh[8704];    // 2x528x8=8448 stage; alias [128][68]
    int t = threadIdx.x, lane = t & 63, wv = t >> 6;
    int m = lane & 15, g = lane >> 4;
    int pw = wv & 1, u2h = wv >> 1;
    int owt = blockIdx.x;
    int by = blockIdx.y; int ohg = by >> 1, ph = by & 1;
    int n = blockIdx.z;
    int col0 = owt * 64;

    const unsigned short* an = in + ((size_t)(n * Hpi + ohg + ph) * Wpi + col0) * 64;
    for (int q = t; q < 1056; q += 256) {
        int r = q / 528, rest = q - r * 528;
        int p = rest >> 3, uu = rest & 7;
        int su = (uu - (p & 7)) & 7;
        gl_lds16(an + ((size_t)r * Wpi + p) * 64 + su * 8, sh + (size_t)q * 8);
    }
    f32x4_t acc[4][2];
#pragma unroll
    for (int a = 0; a < 4; ++a)
#pragma unroll
        for (int u2i = 0; u2i < 2; ++u2i) acc[a][u2i] = (f32x4_t){0.f, 0.f, 0.f, 0.f};
    __syncthreads();

    const uint4* ws4 = (const uint4*)(wp + (size_t)(ph * 2 + pw) * 16384);
#pragma unroll
    for (int jh = 0; jh < 2; ++jh) {
#pragma unroll
        for (int jw = 0; jw < 2; ++jw) {
#pragma unroll
            for (int cs = 0; cs < 2; ++cs) {
                int s = (jh * 2 + jw) * 2 + cs;
                const uint4* wr = ws4 + (size_t)(s * 4 + g) * 64 + m;
                FragU A[4];
#pragma unroll
                for (int a = 0; a < 4; ++a) A[a].u = wr[a * 16];
#pragma unroll
                for (int u2i = 0; u2i < 2; ++u2i) {
                    int u2 = u2h * 2 + u2i;
                    int p = u2 * 16 + m + pw + jw;
                    int off = (cs * 32 + g * 8 + ((p & 7) << 3)) & 63;
                    FragU B;
                    B.u = *(const uint4*)(sh + (size_t)(jh * 528 + p * 8) * 8 + off);
#pragma unroll
                    for (int a = 0; a < 4; ++a)
                        acc[a][u2i] = mfma16(A[a].b, B.b, acc[a][u2i]);
                }
            }
        }
    }
    // epilogue: bias+relu+pack, LDS [128][68] alias, contiguous row store
    unsigned pk[4][2][2];
#pragma unroll
    for (int a = 0; a < 4; ++a) {
        float4 bv = *(const float4*)(bias + a * 16 + g * 4);
#pragma unroll
        for (int u2i = 0; u2i < 2; ++u2i) {
            float v0 = fmaxf(acc[a][u2i][0] + bv.x, 0.f);
            float v1 = fmaxf(acc[a][u2i][1] + bv.y, 0.f);
            float v2 = fmaxf(acc[a][u2i][2] + bv.z, 0.f);
            float v3 = fmaxf(acc[a][u2i][3] + bv.w, 0.f);
            if constexpr (OUTM == 3) { pk[a][u2i][0] = pack2h(v0, v1); pk[a][u2i][1] = pack2h(v2, v3); }
            else                     { pk[a][u2i][0] = pack2(v0, v1);  pk[a][u2i][1] = pack2(v2, v3); }
        }
    }
    __syncthreads();                             // stage reads done before alias
#pragma unroll
    for (int u2i = 0; u2i < 2; ++u2i) {
        int u2 = u2h * 2 + u2i;
        int lp = 2 * (u2 * 16 + m) + pw;         // local pixel 0..127
#pragma unroll
        for (int a = 0; a < 4; ++a)
            *(uint2*)(sh + (size_t)lp * 68 + a * 16 + g * 4) =
                (uint2){pk[a][u2i][0], pk[a][u2i][1]};
    }
    __syncthreads();
    unsigned short* gbase = out + ((size_t)(n * Hpo + 2 * ohg + ph + 1) * Wpo
                          + 2 * col0 + 1) * 64;
#pragma unroll
    for (int i = 0; i < 4; ++i) {
        int s = i * 256 + t;                     // 1024 uint4 slots = 128px x 64ch
        int p = s >> 3, c8 = s & 7;
        uint4 v = *(const uint4*)(sh + (size_t)p * 68 + c8 * 8);
        *(uint4*)(gbase + (size_t)s * 8) = v;
    }
}

// ---- enc4: 3x3 s1 conv 64->512, 128sp x 128co tiles ------------------------
__global__ __launch_bounds__(256) void k_enc4(
    const unsigned short* __restrict__ a3, const unsigned short* __restrict__ wp,
    const float* __restrict__ bias, unsigned short* __restrict__ zH,
    unsigned short* __restrict__ zL)
{
    __shared__ __align__(16) unsigned short sh[16896];
    int t = threadIdx.x, lane = t & 63, wv = t >> 6;
    int wc = wv & 1, wr = wv >> 1;
    int m = lane & 15, g = lane >> 4;
    int L = blockIdx.x;
    int xcd = L & 7, j = L >> 3;
    int cog = j & 3;
    int rt = (j >> 2) + xcd * 32;
    int row0 = rt * 128;
    int n = row0 >> 12;
    int oh0 = (row0 & 4095) >> 6;

    const unsigned short* an = a3 + ((size_t)(n * 66 + oh0) * 66) * 64;
    for (int seg = wv; seg < 33; seg += 4) {
        int slot = seg * 64 + lane;
        if (slot < 2112) {
            int r = slot / 528, rest = slot - r * 528;
            int p = rest >> 3, uu = rest & 7;
            int su = (uu - p) & 7;
            gl_lds16(an + ((size_t)(r * 66 + p)) * 64 + su * 8, sh + (size_t)slot * 8);
        }
    }
    f32x4_t acc[4][4];
#pragma unroll
    for (int a = 0; a < 4; ++a)
#pragma unroll
        for (int b = 0; b < 4; ++b) acc[a][b] = (f32x4_t){0.f, 0.f, 0.f, 0.f};
    __syncthreads();

#pragma unroll
    for (int tap = 0; tap < 9; ++tap) {
        const int kh = tap / 3, kwp = tap % 3;
#pragma unroll
        for (int cs = 0; cs < 2; ++cs) {
            int s = tap * 2 + cs;
            const uint4* wr4 = (const uint4*)wp + (size_t)(s * 4 + g) * 512 + cog * 128 + wc * 64 + m;
            FragU A[4];
#pragma unroll
            for (int ci = 0; ci < 4; ++ci) A[ci].u = wr4[ci * 16];
#pragma unroll
            for (int si = 0; si < 4; ++si) {
                int sp_l = wr * 64 + si * 16 + m;
                int r_l = (sp_l >> 6) + kh;
                int px = (sp_l & 63) + kwp;
                int off = (cs * 4 + g + px) & 7;
                FragU B;
                B.u = *(const uint4*)(sh + ((size_t)(r_l * 528 + px * 8 + off)) * 8);
#pragma unroll
                for (int ci = 0; ci < 4; ++ci)
                    acc[ci][si] = mfma16(A[ci].b, B.b, acc[ci][si]);
            }
        }
    }
    float4 bv[4];
#pragma unroll
    for (int ci = 0; ci < 4; ++ci)
        bv[ci] = *(const float4*)(bias + cog * 128 + wc * 64 + ci * 16 + g * 4);

    __syncthreads();
#pragma unroll
    for (int ci = 0; ci < 4; ++ci) {
#pragma unroll
        for (int si = 0; si < 4; ++si) {
            float v0 = acc[ci][si][0] + bv[ci].x;
            float v1 = acc[ci][si][1] + bv[ci].y;
            float v2 = acc[ci][si][2] + bv[ci].z;
            float v3 = acc[ci][si][3] + bv[ci].w;
            unsigned h0 = pack2h(v0, v1);
            unsigned h1 = pack2h(v2, v3);
            int row = wr * 64 + si * 16 + m;
            int col = wc * 64 + ci * 16 + g * 4;
            *(uint2*)(sh + (size_t)row * 132 + col) = (uint2){h0, h1};
        }
    }
    __syncthreads();
#pragma unroll
    for (int i = 0; i < 8; ++i) {
        int idx = i * 256 + t;
        int row = idx >> 4, c16 = idx & 15;
        uint4 v = *(const uint4*)(sh + (size_t)row * 132 + c16 * 8);
        int col = cog * 128 + c16 * 8;
        int sblk = col >> 5, off = col & 31;
        *(uint4*)(zH + ((size_t)sblk * 32768 + row0 + row) * 32 + off) = v;
    }
    __syncthreads();
#pragma unroll
    for (int ci = 0; ci < 4; ++ci) {
#pragma unroll
        for (int si = 0; si < 4; ++si) {
            float v0 = acc[ci][si][0] + bv[ci].x;
            float v1 = acc[ci][si][1] + bv[ci].y;
            float v2 = acc[ci][si][2] + bv[ci].z;
            float v3 = acc[ci][si][3] + bv[ci].w;
            unsigned h0 = pack2h(v0, v1);
            unsigned h1 = pack2h(v2, v3);
            unsigned l0 = pack2h(v0 - f16lo(h0), v1 - f16hi(h0));
            unsigned l1 = pack2h(v2 - f16lo(h1), v3 - f16hi(h1));
            int row = wr * 64 + si * 16 + m;
            int col = wc * 64 + ci * 16 + g * 4;
            *(uint2*)(sh + (size_t)row * 132 + col) = (uint2){l0, l1};
        }
    }
    __syncthreads();
#pragma unroll
    for (int i = 0; i < 8; ++i) {
        int idx = i * 256 + t;
        int row = idx >> 4, c16 = idx & 15;
        uint4 v = *(const uint4*)(sh + (size_t)row * 132 + c16 * 8);
        int col = cog * 128 + c16 * 8;
        int sblk = col >> 5, off = col & 31;
        *(uint4*)(zL + ((size_t)sblk * 32768 + row0 + row) * 32 + off) = v;
    }
}

// ---- all halo zeroing in one dispatch --------------------------------------
// case 3 fills the idx map halo with code 512 (the reserved zero row).
__global__ __launch_bounds__(256) void k_halo_all(
    unsigned short* a1, unsigned short* a2, unsigned short* a3,
    int* idxb, unsigned short* d1)
{
    if (blockIdx.z == 3) {
        int n = blockIdx.y;
        int per = 2 * 66 + 2 * 64;               // 260 ring pixels
        for (int i = blockIdx.x * 256 + threadIdx.x; i < per; i += gridDim.x * 256) {
            int h, w;
            if (i < 66) { h = 0; w = i; }
            else if (i < 132) { h = 65; w = i - 66; }
            else { int q = i - 132; h = 1 + (q >> 1); w = (q & 1) ? 65 : 0; }
            idxb[((size_t)n * 66 + h) * 66 + w] = 512;
        }
        return;
    }
    unsigned short* buf; int Hp, Wp, PS;
    switch (blockIdx.z) {
        case 0: buf = a1; Hp = 258; Wp = 258; PS = 64; break;
        case 1: buf = a2; Hp = 130; Wp = 130; PS = 64; break;
        case 2: buf = a3; Hp = 66; Wp = 66; PS = 64; break;
        default: buf = d1; Hp = 66; Wp = 66; PS = 64; break;
    }
    int per = 2 * Wp + 2 * (Hp - 2);
    int chunks = PS >> 3;
    int total = per * chunks;
    int n = blockIdx.y;
    for (int i = blockIdx.x * 256 + threadIdx.x; i < total; i += gridDim.x * 256) {
        int pix = i / chunks, c = i - pix * chunks;
        int h, w;
        if (pix < Wp) { h = 0; w = pix; }
        else if (pix < 2 * Wp) { h = Hp - 1; w = pix - Wp; }
        else { int q = pix - 2 * Wp; h = 1 + (q >> 1); w = (q & 1) ? (Wp - 1) : 0; }
        uint4 zz = {0, 0, 0, 0};
        *(uint4*)(buf + (((size_t)n * Hp + h) * Wp + w) * PS + c * 8) = zz;
    }
}

// ---- weight/codebook prep helpers ------------------------------------------
__device__ inline void prep_conv_dev(const float* __restrict__ w,
    unsigned short* __restrict__ o, int Cout, int Cin, int T, int CIC, int idx)
{
    if (idx >= Cout * Cin * T) return;
    int tap = idx % T; int r = idx / T; int ci = r % Cin; int co = r / Cin;
    int chunk = ci / CIC, cil = ci % CIC;
    int k = chunk * (T * CIC) + tap * CIC + cil;
    int s = k >> 5, g = (k >> 3) & 3, j = k & 7;
    o[((size_t)(s * 4 + g) * Cout + co) * 8 + j] = (unsigned short)bf16rne(w[idx]);
}

__device__ inline void prep_wT_dev(const float* __restrict__ w,
    unsigned short* __restrict__ o, int idx)
{
    if (idx >= 65536) return;
    int ci = idx & 63; int r = idx >> 6;
    int jw = r & 1; r >>= 1;
    int jh = r & 1; r >>= 1;
    int co = r & 63; r >>= 6;
    int pw = r & 1; int ph = (r >> 1) & 1;
    int kh = (1 - ph) + 2 * (1 - jh);
    int kw = (1 - pw) + 2 * (1 - jw);
    int k = (jh * 2 + jw) * 64 + ci;
    int s = k >> 5, g = (k >> 3) & 3, j = k & 7;
    o[(size_t)(ph * 2 + pw) * 16384 + ((size_t)(s * 4 + g) * 64 + co) * 8 + j] =
        (unsigned short)bf16rne(w[((ci * 64 + co) * 4 + kh) * 4 + kw]);
}

// ---- all weight/cb/cn2 prep in one dispatch: grid (1152, 9) ----------------
__global__ __launch_bounds__(256) void k_prep_all(
    const float* __restrict__ enc_w2, const float* __restrict__ enc_w3,
    const float* __restrict__ enc_w4, const float* __restrict__ dec_w1,
    const float* __restrict__ tw1, const float* __restrict__ tw2,
    const float* __restrict__ cb,
    unsigned short* __restrict__ wA2, unsigned short* __restrict__ wA3,
    unsigned short* __restrict__ wB1, unsigned short* __restrict__ wB2,
    unsigned short* __restrict__ wC1, unsigned short* __restrict__ wC2,
    unsigned short* __restrict__ cbF, unsigned short* __restrict__ cbB,
    float* __restrict__ cn2)
{
    int idx = blockIdx.x * 256 + threadIdx.x;
    switch (blockIdx.y) {
    case 0: prep_conv_dev(enc_w2, wA2, 64, 64, 16, 64, idx); break;
    case 1: prep_conv_dev(enc_w3, wA3, 64, 64, 16, 64, idx); break;
    case 2: prep_conv_dev(enc_w4, wB1, 512, 64, 9, 64, idx); break;
    case 3: prep_conv_dev(dec_w1, wB2, 64, 512, 9, 64, idx); break;
    case 4: prep_wT_dev(tw1, wC1, idx); break;
    case 5: prep_wT_dev(tw2, wC2, idx); break;
    case 6: {
        if (idx < 262144) {
            int c = idx & 511, k = idx >> 9;
            int cblk = k >> 7, kl = k & 127, s = c >> 5, g = (c >> 3) & 3, j = c & 7;
            size_t off = ((((size_t)cblk * 16 + s) * 4 + g) * 128 + kl) * 8 + j;
            cbF[off] = f16bits(cb[idx]);
        }
    } break;
    case 7: {
        // bf16 codebook for dec1 gather-stage; row 512 = zeros (halo code)
        if (idx < 262144) cbB[idx] = (unsigned short)bf16rne(cb[idx]);
        else if (idx < 262656) cbB[idx] = 0;
    } break;
    default: {
        int code = blockIdx.x * 4 + (threadIdx.x >> 6);
        if (code < 512) {
            int l = threadIdx.x & 63;
            float s = 0.f;
#pragma unroll
            for (int i = 0; i < 8; ++i) {
                float v = cb[code * 512 + l + i * 64];
                s = fmaf(v, v, s);
            }
#pragma unroll
            for (int off = 32; off > 0; off >>= 1) s += __shfl_xor(s, off);
            if (l == 0) cn2[code] = 0.5f * s;
        }
    } break;
    }
}

// ---- enc conv1: Cin=1, 4x4 s2 p1, ReLU -> bf16 NHWC padded ----------------
__global__ __launch_bounds__(256) void k_conv1(const float* __restrict__ x,
    const float* __restrict__ w, const float* __restrict__ b, unsigned short* __restrict__ out)
{
    __shared__ __align__(16) unsigned short sh[128 * 132];
    int t = threadIdx.x;
    int oh = blockIdx.x;
    int n = blockIdx.y;
    int ow = t;
    const float* xn = x + (size_t)n * 262144;
    float xv[16];
#pragma unroll
    for (int kh = 0; kh < 4; ++kh) {
        int ih = 2 * oh - 1 + kh;
        bool rok = (unsigned)ih < 512u;
        int ihc = min(max(ih, 0), 511);
#pragma unroll
        for (int kw = 0; kw < 4; ++kw) {
            int iw = 2 * ow - 1 + kw;
            bool ok = rok && ((unsigned)iw < 512u);
            int iwc = min(max(iw, 0), 511);
            float v = xn[ihc * 512 + iwc];
            xv[kh * 4 + kw] = ok ? v : 0.f;
        }
    }
    unsigned uo[32];
#pragma unroll
    for (int co2 = 0; co2 < 32; ++co2) {
        float a0 = b[2 * co2], a1 = b[2 * co2 + 1];
#pragma unroll
        for (int q = 0; q < 16; ++q) {
            a0 = fmaf(xv[q], w[(2 * co2) * 16 + q], a0);
            a1 = fmaf(xv[q], w[(2 * co2 + 1) * 16 + q], a1);
        }
        uo[co2] = pack2(fmaxf(a0, 0.f), fmaxf(a1, 0.f));
    }
    unsigned short* rowbase = out + (((size_t)n * 258 + oh + 1) * 258 + 1) * 64;
#pragma unroll
    for (int pass = 0; pass < 2; ++pass) {
        if (pass) __syncthreads();               // protect pass-0 reads
        if ((t >> 7) == pass) {
            int p = t & 127;
            unsigned short* rowp = sh + (size_t)p * 132;
#pragma unroll
            for (int i = 0; i < 8; ++i) {
                uint4 st = {uo[4 * i], uo[4 * i + 1], uo[4 * i + 2], uo[4 * i + 3]};
                *(uint4*)(rowp + i * 8) = st;
            }
        }
        __syncthreads();
        unsigned short* gbase = rowbase + (size_t)pass * 8192;
#pragma unroll
        for (int i = 0; i < 4; ++i) {
            int s = i * 256 + t;                 // lane-consecutive slots
            int p = s >> 3, c = s & 7;
            uint4 v = *(const uint4*)(sh + (size_t)p * 132 + c * 8);
            *(uint4*)(gbase + (size_t)s * 8) = v;
        }
    }
}

__device__ inline bool better_sc(float av, int ai, float bv, int bi) {
    return av > bv || (av == bv && ai < bi);
}

// ---- VQ approx GEMM pass-1: fp16 single-term, top-2 per 128-code block -----
__global__ __launch_bounds__(256) void k_vqgemm(
    const unsigned short* __restrict__ zH, const unsigned short* __restrict__ cbF,
    const float* __restrict__ cn2, int* __restrict__ candI)
{
    __shared__ __align__(16) unsigned short shA[20480];  // 2 bufs x (2 steps x 640 slots x 8)
    int t = threadIdx.x, lane = t & 63, wv = t >> 6;
    int wc = wv & 1, wr = wv >> 1;
    int m = lane & 15, g = lane >> 4;
    int L = blockIdx.x;
    int xcd = L & 7, kk = L >> 3;
    int cblk = kk & 3;
    int row0 = ((kk >> 2) + xcd * 32) * 128;

    f32x4_t acc[4][4];
#pragma unroll
    for (int a = 0; a < 4; ++a)
#pragma unroll
        for (int b = 0; b < 4; ++b) acc[a][b] = (f32x4_t){0.f, 0.f, 0.f, 0.f};

    const uint4* bF = (const uint4*)cbF + (size_t)cblk * 8192;

    auto stage = [&](int c, int bi) {
        unsigned short* dst = shA + (size_t)bi * 10240;
        for (int q = t; q < 1280; q += 256) {
            int ss = q / 640, rest = q - ss * 640;
            int r = rest / 5, seg = rest - r * 5;
            int s = c * 2 + ss;
            gl_lds16(zH + ((size_t)s * 32768 + row0 + r) * 32 + (seg & 3) * 8,
                     dst + (size_t)q * 8);
        }
    };

    stage(0, 0);
    __syncthreads();
    for (int c = 0; c < 8; ++c) {
        if (c + 1 < 8) stage(c + 1, (c + 1) & 1);
        const unsigned short* buf = shA + (size_t)(c & 1) * 10240;
#pragma unroll
        for (int ss = 0; ss < 2; ++ss) {
            int s = c * 2 + ss;
            Frag16 B[4];
#pragma unroll
            for (int ni = 0; ni < 4; ++ni)
                B[ni].u = bF[(s * 4 + g) * 128 + wc * 64 + ni * 16 + m];
#pragma unroll
            for (int mi = 0; mi < 4; ++mi) {
                Frag16 A;
                A.u = *(const uint4*)(buf + (size_t)(ss * 5120 + (wr * 64 + mi * 16 + m) * 40 + g * 8));
#pragma unroll
                for (int ni = 0; ni < 4; ++ni)
                    acc[mi][ni] = mfma16h(A.h, B[ni].h, acc[mi][ni]);
            }
        }
        if (c + 1 < 8) __syncthreads();
    }
    // argmax scratch aliases into buffer0 region (barrier-separated).
    float* tV = (float*)shA;                 // [wc2][row128][cand2]
    int*   tI = (int*)(shA + 2048);          // byte off 4096, same shape
    float c2v[4];
#pragma unroll
    for (int ni = 0; ni < 4; ++ni) c2v[ni] = cn2[cblk * 128 + wc * 64 + ni * 16 + m];
    int ixb = cblk * 128 + wc * 64 + m;
#pragma unroll
    for (int mi = 0; mi < 4; ++mi) {
#pragma unroll
        for (int r = 0; r < 4; ++r) {
            float a0 = acc[mi][0][r] - c2v[0];
            float a1 = acc[mi][1][r] - c2v[1];
            float a2 = acc[mi][2][r] - c2v[2];
            float a3 = acc[mi][3][r] - c2v[3];
            bool cA = a1 > a0;
            float p1 = cA ? a1 : a0; int pi1 = cA ? ixb + 16 : ixb;
            float p2 = cA ? a0 : a1; int pi2 = cA ? ixb : ixb + 16;
            bool cB = a3 > a2;
            float q1 = cB ? a3 : a2; int qi1 = cB ? ixb + 48 : ixb + 32;
            float q2 = cB ? a2 : a3; int qi2 = cB ? ixb + 32 : ixb + 48;
            bool cC = q1 > p1;
            float v1 = cC ? q1 : p1; int i1 = cC ? qi1 : pi1;
            float sa = cC ? p1 : q1; int sai = cC ? pi1 : qi1;
            float sb = cC ? q2 : p2; int sbi = cC ? qi2 : pi2;
            bool cD = sb > sa;
            float v2 = cD ? sb : sa; int i2 = cD ? sbi : sai;
#pragma unroll
            for (int off = 1; off < 16; off <<= 1) {
                float o1 = __shfl_xor(v1, off); int oi1 = __shfl_xor(i1, off);
                float o2 = __shfl_xor(v2, off); int oi2 = __shfl_xor(i2, off);
                bool c = o1 > v1;
                float w2 = c ? v1 : v2; int w2i = c ? i1 : i2;
                float u2 = c ? o2 : o1; int u2i = c ? oi2 : oi1;
                v1 = c ? o1 : v1; i1 = c ? oi1 : i1;
                bool cc = u2 > w2;
                v2 = cc ? u2 : w2; i2 = cc ? u2i : w2i;
            }
            if (m == 0) {
                int row = wr * 64 + mi * 16 + g * 4 + r;
                tV[(wc * 128 + row) * 2 + 0] = v1; tI[(wc * 128 + row) * 2 + 0] = i1;
                tV[(wc * 128 + row) * 2 + 1] = v2; tI[(wc * 128 + row) * 2 + 1] = i2;
            }
        }
    }
    __syncthreads();
    if (t < 128) {
        float v1 = tV[t * 2], v2 = tV[t * 2 + 1];
        int i1 = tI[t * 2], i2 = tI[t * 2 + 1];
        float o1 = tV[(128 + t) * 2], o2 = tV[(128 + t) * 2 + 1];
        int oi1 = tI[(128 + t) * 2], oi2 = tI[(128 + t) * 2 + 1];
        bool c = o1 > v1;
        float w2 = c ? v1 : v2; int w2i = c ? i1 : i2;
        float u2 = c ? o2 : o1; int u2i = c ? oi2 : oi1;
        v1 = c ? o1 : v1; i1 = c ? oi1 : i1;
        bool cc = u2 > w2;
        v2 = cc ? u2 : w2; i2 = cc ? u2i : w2i;
        candI[((size_t)cblk * 2 + 0) * 32768 + row0 + t] = i1;
        candI[((size_t)cblk * 2 + 1) * 32768 + row0 + t] = i2;
    }
}

// ---- VQ pass-2: wave-per-row exact fp32 rescore -> idx map + mind ----------
__global__ __launch_bounds__(256) void k_vqfinal(
    const unsigned short* __restrict__ zH, const unsigned short* __restrict__ zL,
    const float* __restrict__ cb, const int* __restrict__ candI,
    int* __restrict__ idxb, float* __restrict__ mind)
{
    int t = threadIdx.x, lane = t & 63, wv = t >> 6;
    int row = blockIdx.x * 4 + wv;
    size_t zoff = ((size_t)(lane >> 2) * 32768 + row) * 32 + (lane & 3) * 8;
    uint4 hu = *(const uint4*)(zH + zoff);
    uint4 lu = *(const uint4*)(zL + zoff);
    float z0 = f16lo(hu.x) + f16lo(lu.x);
    float z1 = f16hi(hu.x) + f16hi(lu.x);
    float z2 = f16lo(hu.y) + f16lo(lu.y);
    float z3 = f16hi(hu.y) + f16hi(lu.y);
    float z4 = f16lo(hu.z) + f16lo(lu.z);
    float z5 = f16hi(hu.z) + f16hi(lu.z);
    float z6 = f16lo(hu.w) + f16lo(lu.w);
    float z7 = f16hi(hu.w) + f16hi(lu.w);
    int mycand = (lane < 8) ? candI[(size_t)lane * 32768 + row] : 0;
    int cands[8];
    float d[8];
#pragma unroll
    for (int s = 0; s < 8; ++s) cands[s] = __shfl(mycand, s);
#pragma unroll
    for (int s = 0; s < 8; ++s) {
        const float* cr = cb + (size_t)cands[s] * 512 + lane * 8;
        float4 c0 = *(const float4*)cr;
        float4 c1 = *(const float4*)(cr + 4);
        float e, dd = 0.f;
        e = z0 - c0.x; dd = fmaf(e, e, dd);
        e = z1 - c0.y; dd = fmaf(e, e, dd);
        e = z2 - c0.z; dd = fmaf(e, e, dd);
        e = z3 - c0.w; dd = fmaf(e, e, dd);
        e = z4 - c1.x; dd = fmaf(e, e, dd);
        e = z5 - c1.y; dd = fmaf(e, e, dd);
        e = z6 - c1.z; dd = fmaf(e, e, dd);
        e = z7 - c1.w; dd = fmaf(e, e, dd);
        d[s] = dd;
    }
#pragma unroll
    for (int off = 1; off < 64; off <<= 1) {
#pragma unroll
        for (int s = 0; s < 8; ++s) d[s] += __shfl_xor(d[s], off);
    }
    float bd = d[0]; int bi_ = cands[0];
#pragma unroll
    for (int s = 1; s < 8; ++s) {
        if (d[s] < bd || (d[s] == bd && cands[s] < bi_)) { bd = d[s]; bi_ = cands[s]; }
    }
    if (lane == 0) {
        int n = row >> 12, hw = row & 4095, h = hw >> 6, w = hw & 63;
        idxb[((size_t)(n * 66 + h + 1)) * 66 + (w + 1)] = bi_;
        mind[row] = bd;
    }
}

// ---- final conv-transpose 64 -> 1, sigmoid (LDS-staged, fp16 dot2) ---------
__global__ __launch_bounds__(256, 4) void k_convt_final2(const unsigned short* __restrict__ xp,
    const float* __restrict__ w, const float* __restrict__ b, float* __restrict__ out)
{
    __shared__ __align__(16) unsigned short shx[3 * 1040 * 8];
    __shared__ __align__(16) unsigned wp[16][32];
    int t = threadIdx.x, lane = t & 63, wv = t >> 6;
    int bx = blockIdx.x, q = blockIdx.y, n = blockIdx.z;
    int colbase = bx * 128;
#pragma unroll
    for (int i = 0; i < 2; ++i) {
        int qq = t + i * 256;
        int tap = qq >> 5, c2 = qq & 31;
        wp[tap][c2] = pack2h(w[(2 * c2) * 16 + tap], w[(2 * c2 + 1) * 16 + tap]);
    }
    const unsigned short* an = xp + (size_t)n * 258 * 258 * 64;
    for (int u_ = wv; u_ < 51; u_ += 4) {
        int r = u_ / 17, seg = u_ % 17;
        int slot = seg * 64 + lane;
        if (slot < 1040) {
            int p = slot >> 3, uu = slot & 7;
            int su = (uu - p) & 7;
            int row = min(2 * q + r, 257);
            const unsigned short* gsrc = an + ((size_t)row * 258 + colbase + p) * 64 + su * 8;
            gl_lds16(gsrc, shx + ((size_t)(r * 1040 + slot)) * 8);
        }
    }
    __syncthreads();
    int ow = bx * 256 + t;
    int kwA = (ow + 1) & 1;
    int cA = ((ow + 1) >> 1) + 1 - colbase;
    int cB = cA - 1;
    float b0 = b[0];
    float acc0 = b0, acc1 = b0, acc2 = b0, acc3 = b0;
#pragma unroll 2
    for (int c8 = 0; c8 < 8; ++c8) {
        uint4 xr[3][2];
#pragma unroll
        for (int r = 0; r < 3; ++r) {
            xr[r][0] = *(const uint4*)(shx + (size_t)(r * 1040 + cB * 8 + ((c8 + cB) & 7)) * 8);
            xr[r][1] = *(const uint4*)(shx + (size_t)(r * 1040 + cA * 8 + ((c8 + cA) & 7)) * 8);
        }
        uint4 wA[4], wB[4];
#pragma unroll
        for (int kh = 0; kh < 4; ++kh) {
            wA[kh] = *(const uint4*)&wp[kh * 4 + kwA][c8 * 4];
            wB[kh] = *(const uint4*)&wp[kh * 4 + kwA + 2][c8 * 4];
        }
        acc0 = dot8(xr[1][1], wA[0], acc0); acc0 = dot8(xr[1][0], wB[0], acc0);
        acc0 = dot8(xr[0][1], wA[2], acc0); acc0 = dot8(xr[0][0], wB[2], acc0);
        acc1 = dot8(xr[1][1], wA[1], acc1); acc1 = dot8(xr[1][0], wB[1], acc1);
        acc1 = dot8(xr[0][1], wA[3], acc1); acc1 = dot8(xr[0][0], wB[3], acc1);
        acc2 = dot8(xr[2][1], wA[0], acc2); acc2 = dot8(xr[2][0], wB[0], acc2);
        acc2 = dot8(xr[1][1], wA[2], acc2); acc2 = dot8(xr[1][0], wB[2], acc2);
        acc3 = dot8(xr[2][1], wA[1], acc3); acc3 = dot8(xr[2][0], wB[1], acc3);
        acc3 = dot8(xr[1][1], wA[3], acc3); acc3 = dot8(xr[1][0], wB[3], acc3);
    }
    float accs[4] = {acc0, acc1, acc2, acc3};
    float* on = out + (size_t)n * 262144;
#pragma unroll
    for (int ro = 0; ro < 4; ++ro) {
        int oh = 4 * q - 1 + ro;
        if ((unsigned)oh < 512u)
            on[(size_t)oh * 512 + ow] = 1.0f / (1.0f + __expf(-accs[ro]));
    }
}

// ---- finalize loss: single-block reduction over mind[32768] ----------------
__global__ __launch_bounds__(256) void k_loss_final(const float* __restrict__ mind,
    float* __restrict__ out)
{
    __shared__ float redd[4];
    int t = threadIdx.x;
    float s = 0.f;
#pragma unroll 4
    for (int i = 0; i < 32; ++i) {
        float4 v = *(const float4*)(mind + i * 1024 + t * 4);
        s += v.x + v.y + v.z + v.w;
    }
#pragma unroll
    for (int off = 1; off < 64; off <<= 1) s += __shfl_xor(s, off);
    if ((t & 63) == 0) redd[t >> 6] = s;
    __syncthreads();
    if (t == 0)
        out[0] = 1.25f * (redd[0] + redd[1] + redd[2] + redd[3]) * (1.0f / 16777216.0f);
}

// ---------------------------------------------------------------------------
extern "C" void kernel_launch(void* const* d_in, const int* in_sizes, int n_in,
                              void* d_out, int out_size, void* d_ws, size_t ws_size,
                              hipStream_t stream)
{
    const float* x      = (const float*)d_in[0];
    const float* enc_w1 = (const float*)d_in[1];
    const float* enc_b1 = (const float*)d_in[2];
    const float* enc_w2 = (const float*)d_in[3];
    const float* enc_b2 = (const float*)d_in[4];
    const float* enc_w3 = (const float*)d_in[5];
    const float* enc_b3 = (const float*)d_in[6];
    const float* enc_w4 = (const float*)d_in[7];
    const float* enc_b4 = (const float*)d_in[8];
    const float* cb     = (const float*)d_in[9];
    const float* dec_w1 = (const float*)d_in[10];
    const float* dec_b1 = (const float*)d_in[11];
    const float* tw1    = (const float*)d_in[12];
    const float* tb1    = (const float*)d_in[13];
    const float* tw2    = (const float*)d_in[14];
    const float* tb2    = (const float*)d_in[15];
    const float* tw3    = (const float*)d_in[16];
    const float* tb3    = (const float*)d_in[17];
    float* out = (float*)d_out;

    unsigned short* a1 = (unsigned short*)d_ws;        // 8*258*258*64
    unsigned short* a2 = a1 + 34076672;                // 8*130*130*64
    unsigned short* a3 = a2 + 8652800;                 // 8*66*66*64
    unsigned short* zH = a3 + 2230272;                 // 16*32768*32 (fp16)
    unsigned short* zL = zH + 16777216;                // 16*32768*32 (fp16)
    unsigned short* zqr = zL + 16777216;               // ex-zq region (reused)
    unsigned short* d1 = zqr + 17842176;               // 8*66*66*64
    unsigned short* wA2 = d1 + 2230272;                // 65536
    unsigned short* wA3 = wA2 + 65536;
    unsigned short* wB1 = wA3 + 65536;                 // 294912
    unsigned short* wB2 = wB1 + 294912;                // 294912
    unsigned short* wC1 = wB2 + 294912;                // 65536
    unsigned short* wC2 = wC1 + 65536;                 // 65536
    unsigned short* cbF = wC2 + 65536;                 // 262144 (fp16 frag)
    float* cn2 = (float*)(cbF + 262144);               // 512
    int*   candI = (int*)(cn2 + 512);                  // 8*32768
    float* mind = (float*)(candI + 262144);            // 32768
    int*   idxb = (int*)zqr;                           // 8*66*66 ints (139KB)
    unsigned short* cbB = zqr + 2 * 34848;             // 513*512 bf16 (525KB)
    unsigned short* pf = zH;                           // dec1 fp16 partials (zH dead after vqfinal; 2 slabs x 16.8MB)

    // consolidated halos + preps
    k_halo_all<<<dim3(65, 8, 5), 256, 0, stream>>>(a1, a2, a3, idxb, d1);
    k_prep_all<<<dim3(1152, 9), 256, 0, stream>>>(
        enc_w2, enc_w3, enc_w4, dec_w1, tw1, tw2, cb,
        wA2, wA3, wB1, wB2, wC1, wC2, cbF, cbB, cn2);

    // pipeline
    k_conv1<<<dim3(256, 8), 256, 0, stream>>>(x, enc_w1, enc_b1, a1);
    k_enc2w<<<dim3(128, 8), 256, 0, stream>>>(a1, wA2, enc_b2, a2);
    conv_mfma<4, 4, 2, 64, 32, 1, 0, 0><<<dim3(2, 64, 8), 256, 0, stream>>>(
        a2, wA3, enc_b3, a3, 130, 130, 64, 1, 64, 1, 66, 66, 1, nullptr);
    k_enc4<<<1024, 256, 0, stream>>>(a3, wB1, enc_b4, zH, zL);
    k_vqgemm<<<1024, 256, 0, stream>>>(zH, cbF, cn2, candI);
    k_vqfinal<<<8192, 256, 0, stream>>>(zH, zL, cb, candI, idxb, mind);
    // dec1 K-split x2, gather-stage from L2-resident cbB via idx map
    conv_mfma<3, 3, 1, 64, 64, 2, 5, 0><<<dim3(2, 64, 8), 256, 0, stream>>>(
        cbB, wB2, dec_b1, pf, 66, 66, 512, 4, 64, 1, 66, 66, 0, idxb);
    k_dec1red<<<1024, 256, 0, stream>>>(pf, dec_b1, d1);
    k_convtf<0><<<dim3(1, 128, 8), 256, 0, stream>>>(d1, wC1, tb1, a2, 66, 66, 130, 130);
    k_convtf<3><<<dim3(2, 256, 8), 256, 0, stream>>>(a2, wC2, tb2, a1, 130, 130, 258, 258);
    k_convt_final2<<<dim3(2, 129, 8), 256, 0, stream>>>(a1, tw3, tb3, out);
    k_loss_final<<<1, 256, 0, stream>>>(mind, out + 2097152);
}